// Round 4
// baseline (174.522 us; speedup 1.0000x reference)
//
#include <hip/hip_runtime.h>
#include <math.h>

#define BETA  0.125f    // 1/sqrt(64)
#define SHIFT 30.0f     // fixed softmax shift; logits bounded in [0.125, 68.5]
#define EPSF  1e-7f

typedef __attribute__((ext_vector_type(8))) short short8;
typedef __attribute__((ext_vector_type(4))) float f32x4;

__device__ __forceinline__ unsigned short bf16_rne(float x) {
  unsigned int u = __float_as_uint(x);
  return (unsigned short)((u + 0x7fffu + ((u >> 16) & 1u)) >> 16);
}
__device__ __forceinline__ float bf16_tof(unsigned short h) {
  return __uint_as_float(((unsigned int)h) << 16);
}
__device__ __forceinline__ void split2(float x, unsigned short& h, unsigned short& l) {
  unsigned int u = __float_as_uint(x);
  unsigned int hr = (u + 0x7fffu + ((u >> 16) & 1u)) & 0xffff0000u;  // RNE hi
  h = (unsigned short)(hr >> 16);
  l = bf16_rne(x - __uint_as_float(hr));
}

#define ZERO_F4 68608   // (262144 + 12288) floats / 4: Tacc + scalar accums

// ---------------------------------------------------------------------------
// Merged projection (r9-proven). Blocks 0..127: V (heavy, first); 128..255: K;
// 256..319: Q. Also zeroes the attention accumulator region.
// ---------------------------------------------------------------------------
__global__ __launch_bounds__(256) void proj_kernel(
    const float* __restrict__ Xq, const float* __restrict__ Xk,
    const float* __restrict__ Xv,
    const float* __restrict__ Wq, const float* __restrict__ bq,
    const float* __restrict__ Wk, const float* __restrict__ bk,
    const float* __restrict__ Wv, const float* __restrict__ bv,
    float* __restrict__ Q0, float* __restrict__ K0, float* __restrict__ V0,
    unsigned short* __restrict__ Qh, unsigned short* __restrict__ Ql,
    unsigned short* __restrict__ Kh, unsigned short* __restrict__ Kl,
    unsigned short* __restrict__ Vh, unsigned short* __restrict__ Vl,
    unsigned short* __restrict__ Vth, unsigned short* __restrict__ Vtl,
    float* __restrict__ zeroRegion)
{
  __shared__ float Xs[64 * 64];
  __shared__ float Ws[64 * 64];
  __shared__ unsigned int Tr[64 * 65];   // dedicated transpose buffer (V only)

  const int bid = blockIdx.x;
  const int tid = threadIdx.x;

  {
    int idx = bid * 256 + tid;
    if (idx < ZERO_F4)
      *(float4*)&zeroRegion[idx * 4] = make_float4(0.f, 0.f, 0.f, 0.f);
  }

  const float *X, *W, *bias;
  float* y0;
  unsigned short *yh, *yl;
  bool dbl;
  int rowBase;
  if (bid < 128)      { X = Xv; W = Wk; bias = bk; y0 = V0; yh = Vh; yl = Vl; rowBase = bid << 6;         dbl = true;  }
  else if (bid < 256) { X = Xk; W = Wk; bias = bk; y0 = K0; yh = Kh; yl = Kl; rowBase = (bid - 128) << 6; dbl = false; }
  else                { X = Xq; W = Wq; bias = bq; y0 = Q0; yh = Qh; yl = Ql; rowBase = (bid - 256) << 6; dbl = false; }

  const int ty = tid >> 4, tx = tid & 15;
  const int ty4 = ty << 2, tx4 = tx << 2;

  float acc[4][4];
#pragma unroll
  for (int j = 0; j < 4; ++j) {
    float bj = bias[tx4 + j];
#pragma unroll
    for (int i = 0; i < 4; ++i) acc[i][j] = bj;
  }

  for (int kc = 0; kc < 4; ++kc) {
#pragma unroll
    for (int q = 0; q < 4; ++q) {
      int f = tid + (q << 8);
      int r = f >> 4, g = f & 15;
      int sw = (r << 6) + ((g ^ (r >> 2)) << 2);
      *(float4*)&Xs[sw] = *(const float4*)&X[(rowBase + r) * 256 + (kc << 6) + (g << 2)];
      *(float4*)&Ws[sw] = *(const float4*)&W[r * 256 + (kc << 6) + (g << 2)];
    }
    __syncthreads();
#pragma unroll 4
    for (int kk = 0; kk < 64; kk += 4) {
      const int gk = kk >> 2;
      float4 xa[4], wb[4];
#pragma unroll
      for (int i = 0; i < 4; ++i)
        xa[i] = *(const float4*)&Xs[((ty4 + i) << 6) + ((gk ^ ty) << 2)];
#pragma unroll
      for (int j = 0; j < 4; ++j)
        wb[j] = *(const float4*)&Ws[((tx4 + j) << 6) + ((gk ^ tx) << 2)];
#pragma unroll
      for (int i = 0; i < 4; ++i)
#pragma unroll
        for (int j = 0; j < 4; ++j)
          acc[i][j] += xa[i].x * wb[j].x + xa[i].y * wb[j].y +
                       xa[i].z * wb[j].z + xa[i].w * wb[j].w;
    }
    __syncthreads();
  }

  if (dbl) {
#pragma unroll
    for (int i = 0; i < 4; ++i) {
      float4 v = make_float4(acc[i][0], acc[i][1], acc[i][2], acc[i][3]);
      *(float4*)&Xs[((ty4 + i) << 6) + ((tx ^ ty) << 2)] = v;
    }
#pragma unroll
    for (int q = 0; q < 4; ++q) {
      int f = tid + (q << 8);
      int r = f >> 4, g = f & 15;
      int sw = (r << 6) + ((g ^ (r >> 2)) << 2);
      *(float4*)&Ws[sw] = *(const float4*)&Wv[(r << 6) + (g << 2)];
    }
#pragma unroll
    for (int j = 0; j < 4; ++j) {
      float bj = bv[tx4 + j];
#pragma unroll
      for (int i = 0; i < 4; ++i) acc[i][j] = bj;
    }
    __syncthreads();
#pragma unroll 4
    for (int kk = 0; kk < 64; kk += 4) {
      const int gk = kk >> 2;
      float4 xa[4], wb[4];
#pragma unroll
      for (int i = 0; i < 4; ++i)
        xa[i] = *(const float4*)&Xs[((ty4 + i) << 6) + ((gk ^ ty) << 2)];
#pragma unroll
      for (int j = 0; j < 4; ++j)
        wb[j] = *(const float4*)&Ws[((tx4 + j) << 6) + ((gk ^ tx) << 2)];
#pragma unroll
      for (int i = 0; i < 4; ++i)
#pragma unroll
        for (int j = 0; j < 4; ++j)
          acc[i][j] += xa[i].x * wb[j].x + xa[i].y * wb[j].y +
                       xa[i].z * wb[j].z + xa[i].w * wb[j].w;
    }
  }

  // expmap0 epilogue in registers + shuffles
  float n2p[4];
#pragma unroll
  for (int i = 0; i < 4; ++i)
    n2p[i] = acc[i][0] * acc[i][0] + acc[i][1] * acc[i][1] +
             acc[i][2] * acc[i][2] + acc[i][3] * acc[i][3];
#pragma unroll
  for (int i = 0; i < 4; ++i) {
    n2p[i] += __shfl_xor(n2p[i], 1);
    n2p[i] += __shfl_xor(n2p[i], 2);
    n2p[i] += __shfl_xor(n2p[i], 4);
    n2p[i] += __shfl_xor(n2p[i], 8);
  }
  unsigned short hv[4][4], lv[4][4];
#pragma unroll
  for (int i = 0; i < 4; ++i) {
    float n = sqrtf(n2p[i]);
    float factor = fminf(3.5f / (n + EPSF), 1.0f);
    float xn = fmaxf(n * factor, EPSF);
    float et = __expf(xn);
    float rt = __builtin_amdgcn_rcpf(et);
    float ch = 0.5f * (et + rt);
    float sh = 0.5f * (et - rt);
    float scale = sh * factor * __builtin_amdgcn_rcpf(xn);
    int row = rowBase + ty4 + i;
    if (tx == 0) y0[row] = ch;
#pragma unroll
    for (int j = 0; j < 4; ++j) split2(acc[i][j] * scale, hv[i][j], lv[i][j]);
    unsigned int* ph = (unsigned int*)(yh + row * 64 + tx4);
    ph[0] = (unsigned int)hv[i][0] | ((unsigned int)hv[i][1] << 16);
    ph[1] = (unsigned int)hv[i][2] | ((unsigned int)hv[i][3] << 16);
    unsigned int* pl = (unsigned int*)(yl + row * 64 + tx4);
    pl[0] = (unsigned int)lv[i][0] | ((unsigned int)lv[i][1] << 16);
    pl[1] = (unsigned int)lv[i][2] | ((unsigned int)lv[i][3] << 16);
  }

  if (dbl) {
    // transposed copies via dedicated LDS buffer; two passes (hi, lo)
#pragma unroll
    for (int i = 0; i < 4; ++i)
#pragma unroll
      for (int j = 0; j < 4; ++j)
        Tr[(ty4 + i) * 65 + tx4 + j] = (unsigned int)hv[i][j];
    __syncthreads();
#pragma unroll
    for (int q = 0; q < 2; ++q) {
      int f = tid + (q << 8);
      int d = f >> 3;
      int seg = (f & 7) << 3;
      unsigned int o[4];
#pragma unroll
      for (int k = 0; k < 4; ++k)
        o[k] = Tr[(seg + 2 * k) * 65 + d] | (Tr[(seg + 2 * k + 1) * 65 + d] << 16);
      *(uint4*)&Vth[d * 8192 + rowBase + seg] = make_uint4(o[0], o[1], o[2], o[3]);
    }
    __syncthreads();
#pragma unroll
    for (int i = 0; i < 4; ++i)
#pragma unroll
      for (int j = 0; j < 4; ++j)
        Tr[(ty4 + i) * 65 + tx4 + j] = (unsigned int)lv[i][j];
    __syncthreads();
#pragma unroll
    for (int q = 0; q < 2; ++q) {
      int f = tid + (q << 8);
      int d = f >> 3;
      int seg = (f & 7) << 3;
      unsigned int o[4];
#pragma unroll
      for (int k = 0; k < 4; ++k)
        o[k] = Tr[(seg + 2 * k) * 65 + d] | (Tr[(seg + 2 * k + 1) * 65 + d] << 16);
      *(uint4*)&Vtl[d * 8192 + rowBase + seg] = make_uint4(o[0], o[1], o[2], o[3]);
    }
  }
}

// ---------------------------------------------------------------------------
// MFMA attention core, BARRIER-FREE direct-L2 streaming version.
// Evidence (R1-R3): K/V/Vt working set is fully L2/L1-resident (FETCH 7-10MB),
// while the LDS staging pipeline (~55% LDS-pipe busy, 3.8M conflict cycles,
// 2 barriers/chunk, 4x cross-wave read redundancy) was the top cycle consumer.
// So: load MFMA B-fragments DIRECTLY from global (per-lane addresses match
// the fragment layout exactly); only the per-wave W matrix round-trips
// through LDS (same-wave lgkmcnt ordering, no __syncthreads anywhere).
// Grid = 1024 blocks x 128 thr: b(2) x sT(32) x slice(16), bid = t*16+slice
// so slice -> XCD affinity (slice%8) keeps each XCD's KV slice L2-local.
// Block = 2 waves x 32 s-rows (si=2 halves fragment traffic per unit work).
// Co-resident blocks on a CU share the same slice -> fragment loads L1-hit.
// Atomics across 16 slices unchanged (R2: do NOT raise slice count).
// ---------------------------------------------------------------------------
__global__ __launch_bounds__(128) void attn_kernel(
    const float* __restrict__ Q0g, const unsigned short* __restrict__ Qh,
    const unsigned short* __restrict__ Ql,
    const float* __restrict__ K0g, const unsigned short* __restrict__ Khg,
    const unsigned short* __restrict__ Klg,
    const float* __restrict__ V0g, const unsigned short* __restrict__ Vhg,
    const unsigned short* __restrict__ Vlg,
    const unsigned short* __restrict__ Vthg, const unsigned short* __restrict__ Vtlg,
    float* __restrict__ Tacc, float* __restrict__ T0acc,
    float* __restrict__ Lacc, float* __restrict__ WCacc)
{
  // LDS: only the per-wave W matrix (32 rows x 40 u16, 16B-aligned rows).
  __shared__ unsigned short LB[2560];   // 5120 B

  const int tid = threadIdx.x;
  const int wave = tid >> 6, lane = tid & 63;
  const int lm = lane & 15;
  const int lg = lane >> 4;
  const int bid = blockIdx.x;          // 1024 blocks
  const int slice = bid & 15;          // SL = 16
  const int t = bid >> 4;              // 0..63
  const int b = t >> 5;
  const int sT = t & 31;
  const int sBase = b * 2048 + sT * 64 + wave * 32;

  unsigned short* wbase = LB + wave * 1280;

  // loop-invariant Q fragments [si][kstep][hi/lo]
  short8 qf[2][2][2];
#pragma unroll
  for (int si = 0; si < 2; ++si)
#pragma unroll
    for (int ks = 0; ks < 2; ++ks) {
      int idx = (sBase + si * 16 + lm) * 64 + ks * 32 + lg * 8;
      qf[si][ks][0] = *(const short8*)(Qh + idx);
      qf[si][ks][1] = *(const short8*)(Ql + idx);
    }
  float q0r[2][4];
#pragma unroll
  for (int si = 0; si < 2; ++si)
#pragma unroll
    for (int r = 0; r < 4; ++r)
      q0r[si][r] = Q0g[sBase + si * 16 + lg * 4 + r];

  f32x4 accT[2][4];
  float Lp[2][4], WCp[2][4], T0p[2][4];
#pragma unroll
  for (int si = 0; si < 2; ++si)
#pragma unroll
    for (int r = 0; r < 4; ++r) {
      Lp[si][r] = 0.f; WCp[si][r] = 0.f; T0p[si][r] = 0.f;
    }
#pragma unroll
  for (int si = 0; si < 2; ++si)
#pragma unroll
    for (int dj = 0; dj < 4; ++dj) accT[si][dj] = f32x4{0.f, 0.f, 0.f, 0.f};

  const int mSliceBase = b * 4096 + slice * 256;   // 8 chunks of 32

  for (int mc = 0; mc < 8; ++mc) {
    const int mCh = mSliceBase + (mc << 5);

    float k0r[2], v0r[2];
#pragma unroll
    for (int mj = 0; mj < 2; ++mj) {
      k0r[mj] = K0g[mCh + mj * 16 + lm];
      v0r[mj] = V0g[mCh + mj * 16 + lm];
    }

    // ---- Phase A per m-block: fragments direct from global (L1/L2-hit) ----
#pragma unroll
    for (int mj = 0; mj < 2; ++mj) {
      f32x4 sims[2], ipv[2];
#pragma unroll
      for (int si = 0; si < 2; ++si) {
        sims[si] = f32x4{0.f, 0.f, 0.f, 0.f};
        ipv[si]  = f32x4{0.f, 0.f, 0.f, 0.f};
      }
#pragma unroll
      for (int ks = 0; ks < 2; ++ks) {
        int goff = (mCh + mj * 16 + lm) * 64 + ks * 32 + lg * 8;
        short8 kh = *(const short8*)&Khg[goff];
        short8 kl = *(const short8*)&Klg[goff];
        short8 vh = *(const short8*)&Vhg[goff];
        short8 vl = *(const short8*)&Vlg[goff];
#pragma unroll
        for (int si = 0; si < 2; ++si) {
          sims[si] = __builtin_amdgcn_mfma_f32_16x16x32_bf16(qf[si][ks][0], kh, sims[si], 0, 0, 0);
          sims[si] = __builtin_amdgcn_mfma_f32_16x16x32_bf16(qf[si][ks][0], kl, sims[si], 0, 0, 0);
          sims[si] = __builtin_amdgcn_mfma_f32_16x16x32_bf16(qf[si][ks][1], kh, sims[si], 0, 0, 0);
          ipv[si]  = __builtin_amdgcn_mfma_f32_16x16x32_bf16(qf[si][ks][0], vh, ipv[si], 0, 0, 0);
          ipv[si]  = __builtin_amdgcn_mfma_f32_16x16x32_bf16(qf[si][ks][0], vl, ipv[si], 0, 0, 0);
          ipv[si]  = __builtin_amdgcn_mfma_f32_16x16x32_bf16(qf[si][ks][1], vh, ipv[si], 0, 0, 0);
        }
      }
      // ---- elementwise: w = e * acosh(-c) * rsq(c^2-1); W -> per-wave LDS ----
#pragma unroll
      for (int si = 0; si < 2; ++si)
#pragma unroll
        for (int r = 0; r < 4; ++r) {
          float c  = ipv[si][r]  - q0r[si][r] * v0r[mj];
          float sm = sims[si][r] - q0r[si][r] * k0r[mj];
          float x = -c;
          float s2 = fmaxf(fmaf(x, x, -1.0f), EPSF);
          float rs = __builtin_amdgcn_rsqf(s2);
          float dist = __logf(fmaf(s2, rs, x));
          float e = __expf(fmaf(-BETA, sm, -SHIFT));
          float w = e * dist * rs;
          unsigned short wu = bf16_rne(w);
          float wb = bf16_tof(wu);
          Lp[si][r]  += e;
          WCp[si][r] += wb * c;
          T0p[si][r] += wb * v0r[mj];
          wbase[(si * 16 + lg * 4 + r) * 40 + mj * 16 + lm] = wu;
        }
    }

    // ---- Phase B: T[s][d] += W[s][m] * V[m][d]  (A=own-wave W, B=Vt global) ----
    {
      short8 wa[2];
#pragma unroll
      for (int si = 0; si < 2; ++si)
        wa[si] = *(const short8*)(wbase + (si * 16 + lm) * 40 + lg * 8);
#pragma unroll
      for (int dj = 0; dj < 4; ++dj) {
        int toff = (dj * 16 + lm) * 8192 + mCh + lg * 8;
        short8 th = *(const short8*)&Vthg[toff];
        short8 tl = *(const short8*)&Vtlg[toff];
#pragma unroll
        for (int si = 0; si < 2; ++si) {
          accT[si][dj] = __builtin_amdgcn_mfma_f32_16x16x32_bf16(wa[si], th, accT[si][dj], 0, 0, 0);
          accT[si][dj] = __builtin_amdgcn_mfma_f32_16x16x32_bf16(wa[si], tl, accT[si][dj], 0, 0, 0);
        }
      }
    }
    // no barrier: W is per-wave, fragments come from global caches
  }

  // reduce row scalars across the 16 col-lanes
#pragma unroll
  for (int si = 0; si < 2; ++si)
#pragma unroll
    for (int r = 0; r < 4; ++r)
#pragma unroll
      for (int off = 1; off < 16; off <<= 1) {
        Lp[si][r]  += __shfl_xor(Lp[si][r], off);
        WCp[si][r] += __shfl_xor(WCp[si][r], off);
        T0p[si][r] += __shfl_xor(T0p[si][r], off);
      }

  // atomic accumulation across slices (HW f32 atomics)
#pragma unroll
  for (int si = 0; si < 2; ++si)
#pragma unroll
    for (int r = 0; r < 4; ++r) {
      int row = sBase + si * 16 + lg * 4 + r;
#pragma unroll
      for (int dj = 0; dj < 4; ++dj)
        unsafeAtomicAdd(&Tacc[row * 64 + dj * 16 + lm], accT[si][dj][r]);
      if (lm == 0) {
        unsafeAtomicAdd(&Lacc[row],  Lp[si][r]);
        unsafeAtomicAdd(&WCacc[row], WCp[si][r]);
        unsafeAtomicAdd(&T0acc[row], T0p[si][r]);
      }
    }
}

// ---------------------------------------------------------------------------
// Combine (r9-proven): one wave per (b,s) row. f32 fast math; f64 only for
// the <t,t> reduction feeding the tangency identity mk = <t,t> + wc^2.
// ---------------------------------------------------------------------------
__global__ __launch_bounds__(256) void combine_kernel(
    const float* __restrict__ Q0, const unsigned short* __restrict__ Qh,
    const unsigned short* __restrict__ Ql,
    const float* __restrict__ Tacc, const float* __restrict__ T0acc,
    const float* __restrict__ Lacc, const float* __restrict__ WCacc,
    float* __restrict__ out)
{
  int wid = (blockIdx.x << 2) + (threadIdx.x >> 6);
  int lane = threadIdx.x & 63;

  int qi = wid * 64 + lane;
  float Tsum = Tacc[qi];
  float T0 = T0acc[wid];
  float L  = Lacc[wid];
  float WC = WCacc[wid];

  float qd = bf16_tof(Qh[qi]) + bf16_tof(Ql[qi]);
  float q0 = Q0[wid];
  float invL = 1.0f / L;
  float td = Tsum * invL;
  float t0 = T0 * invL;
  float wc = WC * invL;

  double tt = (double)td * (double)td;
#pragma unroll
  for (int off = 1; off < 64; off <<= 1) tt += __shfl_xor(tt, off);
  tt -= (double)t0 * (double)t0;
  double mk = tt + (double)wc * (double)wc;

  float un = (float)sqrt(fmax(mk, 1e-12));
  float eu = __expf(un);
  float ru = 1.0f / eu;
  float ch = 0.5f * (eu + ru);
  float shu = 0.5f * (eu - ru) / un;

  float tmd = td + wc * qd;
  float tm0 = t0 + wc * q0;
  float zd = ch * qd + shu * tmd;
  float z0 = ch * q0 + shu * tm0;

  float p2 = zd * zd;
#pragma unroll
  for (int off = 1; off < 64; off <<= 1) p2 += __shfl_xor(p2, off);
  float yn = fmaxf(sqrtf(p2), EPSF);
  float zc = fmaxf(z0, 1.0f + EPSF);
  float dl = __logf(zc + sqrtf(fmaxf(zc * zc - 1.0f, 0.f)));
  out[qi] = dl * zd / yn;
}

// ---------------------------------------------------------------------------
extern "C" void kernel_launch(void* const* d_in, const int* in_sizes, int n_in,
                              void* d_out, int out_size, void* d_ws, size_t ws_size,
                              hipStream_t stream)
{
  const float* queries = (const float*)d_in[0];
  const float* keys    = (const float*)d_in[1];
  const float* values  = (const float*)d_in[2];
  const float* Wq      = (const float*)d_in[3];
  const float* bq      = (const float*)d_in[4];
  const float* Wk      = (const float*)d_in[5];
  const float* bk      = (const float*)d_in[6];
  const float* Wv      = (const float*)d_in[7];
  const float* bv      = (const float*)d_in[8];
  float* out = (float*)d_out;
  float* ws  = (float*)d_ws;

  float* Q0 = ws;                                   // 4096
  float* K0 = ws + 4096;                            // 8192
  float* V0 = ws + 12288;                           // 8192
  unsigned short* Qh  = (unsigned short*)(ws + 20480);
  unsigned short* Ql  = (unsigned short*)(ws + 151552);
  unsigned short* Kh  = (unsigned short*)(ws + 282624);
  unsigned short* Kl  = (unsigned short*)(ws + 544768);
  unsigned short* Vh  = (unsigned short*)(ws + 806912);
  unsigned short* Vl  = (unsigned short*)(ws + 1069056);
  unsigned short* Vth = (unsigned short*)(ws + 1331200);  // [64][8192]
  unsigned short* Vtl = (unsigned short*)(ws + 1593344);
  float* Tacc  = ws + 1855488;                      // 4096*64 = 262144
  float* T0acc = ws + 2117632;                      // 4096
  float* Lacc  = ws + 2121728;                      // 4096
  float* WCacc = ws + 2125824;                      // 4096

  proj_kernel<<<320, 256, 0, stream>>>(queries, keys, values, Wq, bq, Wk, bk,
                                       Wv, bv, Q0, K0, V0, Qh, Ql, Kh, Kl,
                                       Vh, Vl, Vth, Vtl, Tacc);
  attn_kernel<<<1024, 128, 0, stream>>>(
      Q0, Qh, Ql, K0, Kh, Kl, V0, Vh, Vl, Vth, Vtl,
      Tacc, T0acc, Lacc, WCacc);
  combine_kernel<<<1024, 256, 0, stream>>>(
      Q0, Qh, Ql, Tacc, T0acc, Lacc, WCacc, out);
}

// Round 5
// 161.517 us; speedup vs baseline: 1.0805x; 1.0805x over previous
//
#include <hip/hip_runtime.h>
#include <math.h>

#define BETA  0.125f    // 1/sqrt(64)
#define SHIFT 30.0f     // fixed softmax shift; logits bounded in [0.125, 68.5]
#define EPSF  1e-7f

typedef __attribute__((ext_vector_type(8))) short short8;
typedef __attribute__((ext_vector_type(4))) short short4v;
typedef __attribute__((ext_vector_type(4))) float f32x4;

__device__ __forceinline__ unsigned short bf16_rne(float x) {
  unsigned int u = __float_as_uint(x);
  return (unsigned short)((u + 0x7fffu + ((u >> 16) & 1u)) >> 16);
}
__device__ __forceinline__ float bf16_tof(unsigned short h) {
  return __uint_as_float(((unsigned int)h) << 16);
}
__device__ __forceinline__ void split2(float x, unsigned short& h, unsigned short& l) {
  unsigned int u = __float_as_uint(x);
  unsigned int hr = (u + 0x7fffu + ((u >> 16) & 1u)) & 0xffff0000u;  // RNE hi
  h = (unsigned short)(hr >> 16);
  l = bf16_rne(x - __uint_as_float(hr));
}

#define ZERO_F4 68608   // (262144 + 12288) floats / 4: Tacc + scalar accums

// ---------------------------------------------------------------------------
// Merged projection, 512-thread version (2 rows/thread instead of 4).
// Same per-wave access patterns as the 256-thread r9 kernel; 2x the waves
// (1.25 -> 2.5 waves/SIMD) to hide LDS/global latency at the same LDS traffic.
// Blocks 0..127: V (heavy, first); 128..255: K; 256..319: Q.
// Also zeroes the attention accumulator region.
// ---------------------------------------------------------------------------
__global__ __launch_bounds__(512) void proj_kernel(
    const float* __restrict__ Xq, const float* __restrict__ Xk,
    const float* __restrict__ Xv,
    const float* __restrict__ Wq, const float* __restrict__ bq,
    const float* __restrict__ Wk, const float* __restrict__ bk,
    const float* __restrict__ Wv, const float* __restrict__ bv,
    float* __restrict__ Q0, float* __restrict__ K0, float* __restrict__ V0,
    unsigned short* __restrict__ Qh, unsigned short* __restrict__ Ql,
    unsigned short* __restrict__ Kh, unsigned short* __restrict__ Kl,
    unsigned short* __restrict__ Vh, unsigned short* __restrict__ Vl,
    unsigned short* __restrict__ Vth, unsigned short* __restrict__ Vtl,
    float* __restrict__ zeroRegion)
{
  __shared__ float Xs[64 * 64];
  __shared__ float Ws[64 * 64];
  __shared__ unsigned int Tr[64 * 65];   // dedicated transpose buffer (V only)

  const int bid = blockIdx.x;
  const int tid = threadIdx.x;

  {
    int idx = bid * 512 + tid;
    if (idx < ZERO_F4)
      *(float4*)&zeroRegion[idx * 4] = make_float4(0.f, 0.f, 0.f, 0.f);
  }

  const float *X, *W, *bias;
  float* y0;
  unsigned short *yh, *yl;
  bool dbl;
  int rowBase;
  if (bid < 128)      { X = Xv; W = Wk; bias = bk; y0 = V0; yh = Vh; yl = Vl; rowBase = bid << 6;         dbl = true;  }
  else if (bid < 256) { X = Xk; W = Wk; bias = bk; y0 = K0; yh = Kh; yl = Kl; rowBase = (bid - 128) << 6; dbl = false; }
  else                { X = Xq; W = Wq; bias = bq; y0 = Q0; yh = Qh; yl = Ql; rowBase = (bid - 256) << 6; dbl = false; }

  const int ty = tid >> 4;         // 0..31 (2 rows each)
  const int tx = tid & 15;
  const int ty2 = ty << 1, tx4 = tx << 2;
  const int kx = ty >> 1;          // swizzle key for this thread's rows (= row>>2)

  float acc[2][4];
#pragma unroll
  for (int j = 0; j < 4; ++j) {
    float bj = bias[tx4 + j];
#pragma unroll
    for (int i = 0; i < 2; ++i) acc[i][j] = bj;
  }

  for (int kc = 0; kc < 4; ++kc) {
#pragma unroll
    for (int q = 0; q < 2; ++q) {
      int f = tid + (q << 9);
      int r = f >> 4, g = f & 15;
      int sw = (r << 6) + ((g ^ (r >> 2)) << 2);
      *(float4*)&Xs[sw] = *(const float4*)&X[(rowBase + r) * 256 + (kc << 6) + (g << 2)];
      *(float4*)&Ws[sw] = *(const float4*)&W[r * 256 + (kc << 6) + (g << 2)];
    }
    __syncthreads();
#pragma unroll 4
    for (int kk = 0; kk < 64; kk += 4) {
      const int gk = kk >> 2;
      float4 xa[2], wb[4];
#pragma unroll
      for (int i = 0; i < 2; ++i)
        xa[i] = *(const float4*)&Xs[((ty2 + i) << 6) + ((gk ^ kx) << 2)];
#pragma unroll
      for (int j = 0; j < 4; ++j)
        wb[j] = *(const float4*)&Ws[((tx4 + j) << 6) + ((gk ^ tx) << 2)];
#pragma unroll
      for (int i = 0; i < 2; ++i)
#pragma unroll
        for (int j = 0; j < 4; ++j)
          acc[i][j] += xa[i].x * wb[j].x + xa[i].y * wb[j].y +
                       xa[i].z * wb[j].z + xa[i].w * wb[j].w;
    }
    __syncthreads();
  }

  if (dbl) {
#pragma unroll
    for (int i = 0; i < 2; ++i) {
      float4 v = make_float4(acc[i][0], acc[i][1], acc[i][2], acc[i][3]);
      *(float4*)&Xs[((ty2 + i) << 6) + ((tx ^ kx) << 2)] = v;
    }
#pragma unroll
    for (int q = 0; q < 2; ++q) {
      int f = tid + (q << 9);
      int r = f >> 4, g = f & 15;
      int sw = (r << 6) + ((g ^ (r >> 2)) << 2);
      *(float4*)&Ws[sw] = *(const float4*)&Wv[(r << 6) + (g << 2)];
    }
#pragma unroll
    for (int j = 0; j < 4; ++j) {
      float bj = bv[tx4 + j];
#pragma unroll
      for (int i = 0; i < 2; ++i) acc[i][j] = bj;
    }
    __syncthreads();
#pragma unroll 4
    for (int kk = 0; kk < 64; kk += 4) {
      const int gk = kk >> 2;
      float4 xa[2], wb[4];
#pragma unroll
      for (int i = 0; i < 2; ++i)
        xa[i] = *(const float4*)&Xs[((ty2 + i) << 6) + ((gk ^ kx) << 2)];
#pragma unroll
      for (int j = 0; j < 4; ++j)
        wb[j] = *(const float4*)&Ws[((tx4 + j) << 6) + ((gk ^ tx) << 2)];
#pragma unroll
      for (int i = 0; i < 2; ++i)
#pragma unroll
        for (int j = 0; j < 4; ++j)
          acc[i][j] += xa[i].x * wb[j].x + xa[i].y * wb[j].y +
                       xa[i].z * wb[j].z + xa[i].w * wb[j].w;
    }
  }

  // expmap0 epilogue in registers + shuffles (16 tx-lanes per row group)
  float n2p[2];
#pragma unroll
  for (int i = 0; i < 2; ++i)
    n2p[i] = acc[i][0] * acc[i][0] + acc[i][1] * acc[i][1] +
             acc[i][2] * acc[i][2] + acc[i][3] * acc[i][3];
#pragma unroll
  for (int i = 0; i < 2; ++i) {
    n2p[i] += __shfl_xor(n2p[i], 1);
    n2p[i] += __shfl_xor(n2p[i], 2);
    n2p[i] += __shfl_xor(n2p[i], 4);
    n2p[i] += __shfl_xor(n2p[i], 8);
  }
  unsigned short hv[2][4], lv[2][4];
#pragma unroll
  for (int i = 0; i < 2; ++i) {
    float n = sqrtf(n2p[i]);
    float factor = fminf(3.5f / (n + EPSF), 1.0f);
    float xn = fmaxf(n * factor, EPSF);
    float et = __expf(xn);
    float rt = __builtin_amdgcn_rcpf(et);
    float ch = 0.5f * (et + rt);
    float sh = 0.5f * (et - rt);
    float scale = sh * factor * __builtin_amdgcn_rcpf(xn);
    int row = rowBase + ty2 + i;
    if (tx == 0) y0[row] = ch;
#pragma unroll
    for (int j = 0; j < 4; ++j) split2(acc[i][j] * scale, hv[i][j], lv[i][j]);
    unsigned int* ph = (unsigned int*)(yh + row * 64 + tx4);
    ph[0] = (unsigned int)hv[i][0] | ((unsigned int)hv[i][1] << 16);
    ph[1] = (unsigned int)hv[i][2] | ((unsigned int)hv[i][3] << 16);
    unsigned int* pl = (unsigned int*)(yl + row * 64 + tx4);
    pl[0] = (unsigned int)lv[i][0] | ((unsigned int)lv[i][1] << 16);
    pl[1] = (unsigned int)lv[i][2] | ((unsigned int)lv[i][3] << 16);
  }

  if (dbl) {
    // transposed copies via dedicated LDS buffer; two passes (hi, lo)
#pragma unroll
    for (int i = 0; i < 2; ++i)
#pragma unroll
      for (int j = 0; j < 4; ++j)
        Tr[(ty2 + i) * 65 + tx4 + j] = (unsigned int)hv[i][j];
    __syncthreads();
    {
      int f = tid;                     // 0..511 covers [64 d][8 segs]
      int d = f >> 3;
      int seg = (f & 7) << 3;
      unsigned int o[4];
#pragma unroll
      for (int k = 0; k < 4; ++k)
        o[k] = Tr[(seg + 2 * k) * 65 + d] | (Tr[(seg + 2 * k + 1) * 65 + d] << 16);
      *(uint4*)&Vth[d * 8192 + rowBase + seg] = make_uint4(o[0], o[1], o[2], o[3]);
    }
    __syncthreads();
#pragma unroll
    for (int i = 0; i < 2; ++i)
#pragma unroll
      for (int j = 0; j < 4; ++j)
        Tr[(ty2 + i) * 65 + tx4 + j] = (unsigned int)lv[i][j];
    __syncthreads();
    {
      int f = tid;
      int d = f >> 3;
      int seg = (f & 7) << 3;
      unsigned int o[4];
#pragma unroll
      for (int k = 0; k < 4; ++k)
        o[k] = Tr[(seg + 2 * k) * 65 + d] | (Tr[(seg + 2 * k + 1) * 65 + d] << 16);
      *(uint4*)&Vtl[d * 8192 + rowBase + seg] = make_uint4(o[0], o[1], o[2], o[3]);
    }
  }
}

// ---------------------------------------------------------------------------
// MFMA attention core — R1-proven structure (best: 47.7 us), LDS trimmed to
// 32,256 B for 5 blocks/CU (20 waves/CU, +25% latency hiding vs R1's 4).
// Vt tiles stride 40 -> 36 u16 (rows 8B-aligned; 2x ds_read_b64 like W).
// R2 lesson: 16 slices only (atomic traffic). R3 lesson: no reg-prefetch.
// R4 lesson: K/V fragments MUST come from LDS, not global.
// Grid = 1024: b(2) x sT(32) x slice(16). Block = 4 waves x 16 s-rows;
// m-slice = 256 = 8 chunks of 32. 2 barriers/chunk.
// ---------------------------------------------------------------------------
__global__ void __attribute__((amdgpu_waves_per_eu(5)))
__launch_bounds__(256) attn_kernel(
    const float* __restrict__ Q0g, const unsigned short* __restrict__ Qh,
    const unsigned short* __restrict__ Ql,
    const float* __restrict__ K0g, const unsigned short* __restrict__ Khg,
    const unsigned short* __restrict__ Klg,
    const float* __restrict__ V0g, const unsigned short* __restrict__ Vhg,
    const unsigned short* __restrict__ Vlg,
    const unsigned short* __restrict__ Vthg, const unsigned short* __restrict__ Vtlg,
    float* __restrict__ Tacc, float* __restrict__ T0acc,
    float* __restrict__ Lacc, float* __restrict__ WCacc)
{
  // LDS layout (u16 units):
  //   Kh@0  Kl@2304  Vh@4608  Vl@6912   (each 32 rows x 72, 16B-aligned rows)
  //   Vth@9216  Vtl@11520               (each 64 rows x 36, 8B-aligned rows)
  //   W@13824 + wave*576                (per-wave 16 x 36, dedicated)
  __shared__ unsigned short LB[16128];   // 32,256 B -> 5 blocks/CU

  const int tid = threadIdx.x;
  const int wave = tid >> 6, lane = tid & 63;
  const int lm = lane & 15;
  const int lg = lane >> 4;
  const int bid = blockIdx.x;          // 1024 blocks
  const int slice = bid & 15;          // SL = 16
  const int t = bid >> 4;              // 0..63
  const int b = t >> 5;
  const int sT = t & 31;
  const int sBase = b * 2048 + sT * 64 + wave * 16;

  unsigned short* wbase = LB + 13824 + wave * 576;

  // loop-invariant Q fragments [kstep][hi/lo]
  short8 qf[2][2];
#pragma unroll
  for (int ks = 0; ks < 2; ++ks) {
    int idx = (sBase + lm) * 64 + ks * 32 + lg * 8;
    qf[ks][0] = *(const short8*)(Qh + idx);
    qf[ks][1] = *(const short8*)(Ql + idx);
  }
  float q0r[4];
#pragma unroll
  for (int r = 0; r < 4; ++r) q0r[r] = Q0g[sBase + lg * 4 + r];

  f32x4 accT[4];
  float Lp[4], WCp[4], T0p[4];
#pragma unroll
  for (int r = 0; r < 4; ++r) { Lp[r] = 0.f; WCp[r] = 0.f; T0p[r] = 0.f; }
#pragma unroll
  for (int dj = 0; dj < 4; ++dj) accT[dj] = f32x4{0.f, 0.f, 0.f, 0.f};

  const int mSliceBase = b * 4096 + slice * 256;   // 8 chunks of 32
  const int srow = tid >> 3;            // 0..31 (K/V tile row)
  const int sc8 = (tid & 7) << 3;       // 0,8,..,56
  const int drow = tid >> 2;            // 0..63 (Vt tile row = d)
  const int dseg = (tid & 3) << 3;      // 0,8,16,24

  for (int mc = 0; mc < 8; ++mc) {
    const int mCh = mSliceBase + (mc << 5);

    // ---- stage 6 tiles ----
    {
      int goff = (mCh + srow) * 64 + sc8;
      int loff = srow * 72 + sc8;
      *(uint4*)&LB[loff]         = *(const uint4*)&Khg[goff];
      *(uint4*)&LB[2304 + loff]  = *(const uint4*)&Klg[goff];
      *(uint4*)&LB[4608 + loff]  = *(const uint4*)&Vhg[goff];
      *(uint4*)&LB[6912 + loff]  = *(const uint4*)&Vlg[goff];
      int gofft = drow * 8192 + mCh + dseg;        // Vt global: [d][8192]
      int lofft = drow * 36 + dseg;
      uint4 vt0 = *(const uint4*)&Vthg[gofft];
      uint4 vt1 = *(const uint4*)&Vtlg[gofft];
      *(uint2*)&LB[9216 + lofft]      = make_uint2(vt0.x, vt0.y);
      *(uint2*)&LB[9216 + lofft + 4]  = make_uint2(vt0.z, vt0.w);
      *(uint2*)&LB[11520 + lofft]     = make_uint2(vt1.x, vt1.y);
      *(uint2*)&LB[11520 + lofft + 4] = make_uint2(vt1.z, vt1.w);
    }
    float k0r[2], v0r[2];
#pragma unroll
    for (int mj = 0; mj < 2; ++mj) {
      k0r[mj] = K0g[mCh + mj * 16 + lm];
      v0r[mj] = V0g[mCh + mj * 16 + lm];
    }
    __syncthreads();

    // ---- per m-block: sims/ipv MFMAs + elementwise + W write ----
#pragma unroll
    for (int mj = 0; mj < 2; ++mj) {
      f32x4 sims = f32x4{0.f, 0.f, 0.f, 0.f};
      f32x4 ipv  = f32x4{0.f, 0.f, 0.f, 0.f};
#pragma unroll
      for (int ks = 0; ks < 2; ++ks) {
        int off = (mj * 16 + lm) * 72 + ks * 32 + lg * 8;
        short8 kh = *(const short8*)&LB[off];
        short8 kl = *(const short8*)&LB[2304 + off];
        short8 vh = *(const short8*)&LB[4608 + off];
        short8 vl = *(const short8*)&LB[6912 + off];
        sims = __builtin_amdgcn_mfma_f32_16x16x32_bf16(qf[ks][0], kh, sims, 0, 0, 0);
        sims = __builtin_amdgcn_mfma_f32_16x16x32_bf16(qf[ks][0], kl, sims, 0, 0, 0);
        sims = __builtin_amdgcn_mfma_f32_16x16x32_bf16(qf[ks][1], kh, sims, 0, 0, 0);
        ipv  = __builtin_amdgcn_mfma_f32_16x16x32_bf16(qf[ks][0], vh, ipv, 0, 0, 0);
        ipv  = __builtin_amdgcn_mfma_f32_16x16x32_bf16(qf[ks][0], vl, ipv, 0, 0, 0);
        ipv  = __builtin_amdgcn_mfma_f32_16x16x32_bf16(qf[ks][1], vh, ipv, 0, 0, 0);
      }
      // w = e * acosh(-c) * rsq(c^2-1)
#pragma unroll
      for (int r = 0; r < 4; ++r) {
        float c  = ipv[r]  - q0r[r] * v0r[mj];
        float sm = sims[r] - q0r[r] * k0r[mj];
        float x = -c;
        float s2 = fmaxf(fmaf(x, x, -1.0f), EPSF);
        float rs = __builtin_amdgcn_rsqf(s2);
        float dist = __logf(fmaf(s2, rs, x));
        float e = __expf(fmaf(-BETA, sm, -SHIFT));
        float w = e * dist * rs;
        unsigned short wu = bf16_rne(w);
        float wb = bf16_tof(wu);
        Lp[r]  += e;
        WCp[r] += wb * c;
        T0p[r] += wb * v0r[mj];
        wbase[(lg * 4 + r) * 36 + mj * 16 + lm] = wu;
      }
    }

    // ---- Phase B: T[s][d] += W[s][m] * V[m][d]  (A=own-wave W, B=Vt) ----
    {
      short8 wa;
      {
        const unsigned short* p = wbase + lm * 36 + lg * 8;
        short4v a0 = *(const short4v*)p;
        short4v a1 = *(const short4v*)(p + 4);
        wa = __builtin_shufflevector(a0, a1, 0, 1, 2, 3, 4, 5, 6, 7);
      }
#pragma unroll
      for (int dj = 0; dj < 4; ++dj) {
        int off = (dj * 16 + lm) * 36 + lg * 8;
        short4v h0 = *(const short4v*)&LB[9216 + off];
        short4v h1 = *(const short4v*)&LB[9216 + off + 4];
        short4v l0 = *(const short4v*)&LB[11520 + off];
        short4v l1 = *(const short4v*)&LB[11520 + off + 4];
        short8 th = __builtin_shufflevector(h0, h1, 0, 1, 2, 3, 4, 5, 6, 7);
        short8 tl = __builtin_shufflevector(l0, l1, 0, 1, 2, 3, 4, 5, 6, 7);
        accT[dj] = __builtin_amdgcn_mfma_f32_16x16x32_bf16(wa, th, accT[dj], 0, 0, 0);
        accT[dj] = __builtin_amdgcn_mfma_f32_16x16x32_bf16(wa, tl, accT[dj], 0, 0, 0);
      }
    }
    __syncthreads();  // tiles consumed before next chunk's staging
  }

  // reduce row scalars across the 16 col-lanes
#pragma unroll
  for (int r = 0; r < 4; ++r)
#pragma unroll
    for (int off = 1; off < 16; off <<= 1) {
      Lp[r]  += __shfl_xor(Lp[r], off);
      WCp[r] += __shfl_xor(WCp[r], off);
      T0p[r] += __shfl_xor(T0p[r], off);
    }

  // atomic accumulation across slices (HW f32 atomics)
#pragma unroll
  for (int r = 0; r < 4; ++r) {
    int row = sBase + lg * 4 + r;
#pragma unroll
    for (int dj = 0; dj < 4; ++dj)
      unsafeAtomicAdd(&Tacc[row * 64 + dj * 16 + lm], accT[dj][r]);
    if (lm == 0) {
      unsafeAtomicAdd(&Lacc[row],  Lp[r]);
      unsafeAtomicAdd(&WCacc[row], WCp[r]);
      unsafeAtomicAdd(&T0acc[row], T0p[r]);
    }
  }
}

// ---------------------------------------------------------------------------
// Combine (r9-proven): one wave per (b,s) row. f32 fast math; f64 only for
// the <t,t> reduction feeding the tangency identity mk = <t,t> + wc^2.
// ---------------------------------------------------------------------------
__global__ __launch_bounds__(256) void combine_kernel(
    const float* __restrict__ Q0, const unsigned short* __restrict__ Qh,
    const unsigned short* __restrict__ Ql,
    const float* __restrict__ Tacc, const float* __restrict__ T0acc,
    const float* __restrict__ Lacc, const float* __restrict__ WCacc,
    float* __restrict__ out)
{
  int wid = (blockIdx.x << 2) + (threadIdx.x >> 6);
  int lane = threadIdx.x & 63;

  int qi = wid * 64 + lane;
  float Tsum = Tacc[qi];
  float T0 = T0acc[wid];
  float L  = Lacc[wid];
  float WC = WCacc[wid];

  float qd = bf16_tof(Qh[qi]) + bf16_tof(Ql[qi]);
  float q0 = Q0[wid];
  float invL = 1.0f / L;
  float td = Tsum * invL;
  float t0 = T0 * invL;
  float wc = WC * invL;

  double tt = (double)td * (double)td;
#pragma unroll
  for (int off = 1; off < 64; off <<= 1) tt += __shfl_xor(tt, off);
  tt -= (double)t0 * (double)t0;
  double mk = tt + (double)wc * (double)wc;

  float un = (float)sqrt(fmax(mk, 1e-12));
  float eu = __expf(un);
  float ru = 1.0f / eu;
  float ch = 0.5f * (eu + ru);
  float shu = 0.5f * (eu - ru) / un;

  float tmd = td + wc * qd;
  float tm0 = t0 + wc * q0;
  float zd = ch * qd + shu * tmd;
  float z0 = ch * q0 + shu * tm0;

  float p2 = zd * zd;
#pragma unroll
  for (int off = 1; off < 64; off <<= 1) p2 += __shfl_xor(p2, off);
  float yn = fmaxf(sqrtf(p2), EPSF);
  float zc = fmaxf(z0, 1.0f + EPSF);
  float dl = __logf(zc + sqrtf(fmaxf(zc * zc - 1.0f, 0.f)));
  out[qi] = dl * zd / yn;
}

// ---------------------------------------------------------------------------
extern "C" void kernel_launch(void* const* d_in, const int* in_sizes, int n_in,
                              void* d_out, int out_size, void* d_ws, size_t ws_size,
                              hipStream_t stream)
{
  const float* queries = (const float*)d_in[0];
  const float* keys    = (const float*)d_in[1];
  const float* values  = (const float*)d_in[2];
  const float* Wq      = (const float*)d_in[3];
  const float* bq      = (const float*)d_in[4];
  const float* Wk      = (const float*)d_in[5];
  const float* bk      = (const float*)d_in[6];
  const float* Wv      = (const float*)d_in[7];
  const float* bv      = (const float*)d_in[8];
  float* out = (float*)d_out;
  float* ws  = (float*)d_ws;

  float* Q0 = ws;                                   // 4096
  float* K0 = ws + 4096;                            // 8192
  float* V0 = ws + 12288;                           // 8192
  unsigned short* Qh  = (unsigned short*)(ws + 20480);
  unsigned short* Ql  = (unsigned short*)(ws + 151552);
  unsigned short* Kh  = (unsigned short*)(ws + 282624);
  unsigned short* Kl  = (unsigned short*)(ws + 544768);
  unsigned short* Vh  = (unsigned short*)(ws + 806912);
  unsigned short* Vl  = (unsigned short*)(ws + 1069056);
  unsigned short* Vth = (unsigned short*)(ws + 1331200);  // [64][8192]
  unsigned short* Vtl = (unsigned short*)(ws + 1593344);
  float* Tacc  = ws + 1855488;                      // 4096*64 = 262144
  float* T0acc = ws + 2117632;                      // 4096
  float* Lacc  = ws + 2121728;                      // 4096
  float* WCacc = ws + 2125824;                      // 4096

  proj_kernel<<<320, 512, 0, stream>>>(queries, keys, values, Wq, bq, Wk, bk,
                                       Wv, bv, Q0, K0, V0, Qh, Ql, Kh, Kl,
                                       Vh, Vl, Vth, Vtl, Tacc);
  attn_kernel<<<1024, 256, 0, stream>>>(
      Q0, Qh, Ql, K0, Kh, Kl, V0, Vh, Vl, Vth, Vtl,
      Tacc, T0acc, Lacc, WCacc);
  combine_kernel<<<1024, 256, 0, stream>>>(
      Q0, Qh, Ql, Tacc, T0acc, Lacc, WCacc, out);
}

// Round 6
// 144.642 us; speedup vs baseline: 1.2066x; 1.1167x over previous
//
#include <hip/hip_runtime.h>
#include <math.h>

#define BETA  0.125f    // 1/sqrt(64)
#define SHIFT 30.0f     // fixed softmax shift; logits bounded in [0.125, 68.5]
#define EPSF  1e-7f

typedef __attribute__((ext_vector_type(8))) short short8;
typedef __attribute__((ext_vector_type(4))) short short4v;
typedef __attribute__((ext_vector_type(4))) float f32x4;

__device__ __forceinline__ unsigned short bf16_rne(float x) {
  unsigned int u = __float_as_uint(x);
  return (unsigned short)((u + 0x7fffu + ((u >> 16) & 1u)) >> 16);
}
__device__ __forceinline__ float bf16_tof(unsigned short h) {
  return __uint_as_float(((unsigned int)h) << 16);
}
__device__ __forceinline__ void split2(float x, unsigned short& h, unsigned short& l) {
  unsigned int u = __float_as_uint(x);
  unsigned int hr = (u + 0x7fffu + ((u >> 16) & 1u)) & 0xffff0000u;  // RNE hi
  h = (unsigned short)(hr >> 16);
  l = bf16_rne(x - __uint_as_float(hr));
}
// split 8 consecutive f32 (two float4) into hi/lo bf16 short8 fragments
__device__ __forceinline__ void split8(float4 a, float4 b, short8& h8, short8& l8) {
  unsigned short h, l;
  split2(a.x, h, l); h8[0] = (short)h; l8[0] = (short)l;
  split2(a.y, h, l); h8[1] = (short)h; l8[1] = (short)l;
  split2(a.z, h, l); h8[2] = (short)h; l8[2] = (short)l;
  split2(a.w, h, l); h8[3] = (short)h; l8[3] = (short)l;
  split2(b.x, h, l); h8[4] = (short)h; l8[4] = (short)l;
  split2(b.y, h, l); h8[5] = (short)h; l8[5] = (short)l;
  split2(b.z, h, l); h8[6] = (short)h; l8[6] = (short)l;
  split2(b.w, h, l); h8[7] = (short)h; l8[7] = (short)l;
}

#define ZERO_F4 68608   // (262144 + 12288) floats / 4: Tacc + scalar accums

// ---------------------------------------------------------------------------
// MFMA projection. 320 blocks x 256 thr; blocks 0..127: V (two chained GEMMs),
// 128..255: K, 256..319: Q. Each 4-wave block computes a 64-row x 64-col
// output tile; wave w owns rows rowBase + w*16 .. +15.
// GEMM via split-bf16 MFMA (Ah*Bh + Ah*Bl + Al*Bh), K=256 in 8 ksteps of 32 —
// the SAME decomposition attention Phase A uses (proven numerics).
// A-frags (X rows) are loaded f32 and split once into registers; B-frags
// (W rows, L2-hot) are loaded f32 and split on the fly. No LDS for the GEMM.
// V's second GEMM (K=64) round-trips through a per-wave LDS tile (split bf16).
// MFMA C/D layout: col = lane&15 (out-dim), row = (lane>>4)*4 + r (s-row).
// Also zeroes the attention accumulator region.
// ---------------------------------------------------------------------------
__global__ __launch_bounds__(256) void proj_kernel(
    const float* __restrict__ Xq, const float* __restrict__ Xk,
    const float* __restrict__ Xv,
    const float* __restrict__ Wq, const float* __restrict__ bq,
    const float* __restrict__ Wk, const float* __restrict__ bk,
    const float* __restrict__ Wv, const float* __restrict__ bv,
    float* __restrict__ Q0, float* __restrict__ K0, float* __restrict__ V0,
    unsigned short* __restrict__ Qh, unsigned short* __restrict__ Ql,
    unsigned short* __restrict__ Kh, unsigned short* __restrict__ Kl,
    unsigned short* __restrict__ Vh, unsigned short* __restrict__ Vl,
    unsigned short* __restrict__ Vth, unsigned short* __restrict__ Vtl,
    float* __restrict__ zeroRegion)
{
  __shared__ unsigned int Tr[64 * 65];            // V transpose buffer
  __shared__ unsigned short VkL[4][2][16 * 72];   // per-wave stage-2 A tiles (h,l)

  const int bid = blockIdx.x;
  const int tid = threadIdx.x;

  {
    int idx = bid * 256 + tid;
    if (idx < ZERO_F4)
      *(float4*)&zeroRegion[idx * 4] = make_float4(0.f, 0.f, 0.f, 0.f);
  }

  const float *X, *W, *bias;
  float* y0;
  unsigned short *yh, *yl;
  bool dbl;
  int rowBase;
  if (bid < 128)      { X = Xv; W = Wk; bias = bk; y0 = V0; yh = Vh; yl = Vl; rowBase = bid << 6;         dbl = true;  }
  else if (bid < 256) { X = Xk; W = Wk; bias = bk; y0 = K0; yh = Kh; yl = Kl; rowBase = (bid - 128) << 6; dbl = false; }
  else                { X = Xq; W = Wq; bias = bq; y0 = Q0; yh = Qh; yl = Ql; rowBase = (bid - 256) << 6; dbl = false; }

  const int wave = tid >> 6, lane = tid & 63;
  const int lm = lane & 15;
  const int lg = lane >> 4;
  const int rowB = rowBase + (wave << 4);   // this wave's 16 rows

  // ---- A-fragments: X rows, f32 -> split bf16, kept in registers ----
  short8 Ah[8], Al[8];
  {
    const float* Xr = X + (rowB + lm) * 256 + lg * 8;
#pragma unroll
    for (int ks = 0; ks < 8; ++ks) {
      float4 x0 = *(const float4*)&Xr[ks * 32];
      float4 x1 = *(const float4*)&Xr[ks * 32 + 4];
      split8(x0, x1, Ah[ks], Al[ks]);
    }
  }

  // ---- stage-1 GEMM: acc[nj] = X . W^T + bias (K = 256) ----
  f32x4 acc[4];
#pragma unroll
  for (int nj = 0; nj < 4; ++nj) {
    float b = bias[nj * 16 + lm];
    acc[nj] = f32x4{b, b, b, b};
  }
#pragma unroll
  for (int nj = 0; nj < 4; ++nj) {
    const float* Wr = W + (nj * 16 + lm) * 256 + lg * 8;
#pragma unroll
    for (int ks = 0; ks < 8; ++ks) {
      float4 w0 = *(const float4*)&Wr[ks * 32];
      float4 w1 = *(const float4*)&Wr[ks * 32 + 4];
      short8 Bh, Bl;
      split8(w0, w1, Bh, Bl);
      acc[nj] = __builtin_amdgcn_mfma_f32_16x16x32_bf16(Ah[ks], Bh, acc[nj], 0, 0, 0);
      acc[nj] = __builtin_amdgcn_mfma_f32_16x16x32_bf16(Ah[ks], Bl, acc[nj], 0, 0, 0);
      acc[nj] = __builtin_amdgcn_mfma_f32_16x16x32_bf16(Al[ks], Bh, acc[nj], 0, 0, 0);
    }
  }

  // ---- stage-2 for V: Ve = Vk . Wv^T + bv (K = 64), via per-wave LDS ----
  if (dbl) {
    unsigned short* vh_ = &VkL[wave][0][0];
    unsigned short* vl_ = &VkL[wave][1][0];
#pragma unroll
    for (int nj = 0; nj < 4; ++nj)
#pragma unroll
      for (int r = 0; r < 4; ++r) {
        unsigned short h, l;
        split2(acc[nj][r], h, l);
        vh_[(lg * 4 + r) * 72 + nj * 16 + lm] = h;
        vl_[(lg * 4 + r) * 72 + nj * 16 + lm] = l;
      }
    __syncthreads();
    short8 A2h[2], A2l[2];
#pragma unroll
    for (int ks = 0; ks < 2; ++ks) {
      A2h[ks] = *(const short8*)&vh_[lm * 72 + ks * 32 + lg * 8];
      A2l[ks] = *(const short8*)&vl_[lm * 72 + ks * 32 + lg * 8];
    }
#pragma unroll
    for (int nj = 0; nj < 4; ++nj) {
      float b = bv[nj * 16 + lm];
      acc[nj] = f32x4{b, b, b, b};
    }
#pragma unroll
    for (int nj = 0; nj < 4; ++nj) {
      const float* Wr = Wv + (nj * 16 + lm) * 64 + lg * 8;
#pragma unroll
      for (int ks = 0; ks < 2; ++ks) {
        float4 w0 = *(const float4*)&Wr[ks * 32];
        float4 w1 = *(const float4*)&Wr[ks * 32 + 4];
        short8 Bh, Bl;
        split8(w0, w1, Bh, Bl);
        acc[nj] = __builtin_amdgcn_mfma_f32_16x16x32_bf16(A2h[ks], Bh, acc[nj], 0, 0, 0);
        acc[nj] = __builtin_amdgcn_mfma_f32_16x16x32_bf16(A2h[ks], Bl, acc[nj], 0, 0, 0);
        acc[nj] = __builtin_amdgcn_mfma_f32_16x16x32_bf16(A2l[ks], Bh, acc[nj], 0, 0, 0);
      }
    }
  }

  // ---- expmap0 epilogue: row = rowB + lg*4 + r, cols nj*16 + lm ----
  float n2p[4];
#pragma unroll
  for (int r = 0; r < 4; ++r)
    n2p[r] = acc[0][r] * acc[0][r] + acc[1][r] * acc[1][r] +
             acc[2][r] * acc[2][r] + acc[3][r] * acc[3][r];
#pragma unroll
  for (int r = 0; r < 4; ++r) {
    n2p[r] += __shfl_xor(n2p[r], 1);
    n2p[r] += __shfl_xor(n2p[r], 2);
    n2p[r] += __shfl_xor(n2p[r], 4);
    n2p[r] += __shfl_xor(n2p[r], 8);
  }
  unsigned short hv[4][4], lv[4][4];   // [r][nj]
#pragma unroll
  for (int r = 0; r < 4; ++r) {
    float n = sqrtf(n2p[r]);
    float factor = fminf(3.5f / (n + EPSF), 1.0f);
    float xn = fmaxf(n * factor, EPSF);
    float et = __expf(xn);
    float rt = __builtin_amdgcn_rcpf(et);
    float ch = 0.5f * (et + rt);
    float sh = 0.5f * (et - rt);
    float scale = sh * factor * __builtin_amdgcn_rcpf(xn);
    int row = rowB + lg * 4 + r;
    if (lm == 0) y0[row] = ch;
#pragma unroll
    for (int nj = 0; nj < 4; ++nj) {
      split2(acc[nj][r] * scale, hv[r][nj], lv[r][nj]);
      yh[row * 64 + nj * 16 + lm] = hv[r][nj];
      yl[row * 64 + nj * 16 + lm] = lv[r][nj];
    }
  }

  // ---- V transposed copies via Tr (two passes: hi, lo) ----
  if (dbl) {
#pragma unroll
    for (int r = 0; r < 4; ++r)
#pragma unroll
      for (int nj = 0; nj < 4; ++nj)
        Tr[(wave * 16 + lg * 4 + r) * 65 + nj * 16 + lm] = (unsigned int)hv[r][nj];
    __syncthreads();
#pragma unroll
    for (int q = 0; q < 2; ++q) {
      int f = tid + (q << 8);
      int d = f >> 3;
      int seg = (f & 7) << 3;
      unsigned int o[4];
#pragma unroll
      for (int k = 0; k < 4; ++k)
        o[k] = Tr[(seg + 2 * k) * 65 + d] | (Tr[(seg + 2 * k + 1) * 65 + d] << 16);
      *(uint4*)&Vth[d * 8192 + rowBase + seg] = make_uint4(o[0], o[1], o[2], o[3]);
    }
    __syncthreads();
#pragma unroll
    for (int r = 0; r < 4; ++r)
#pragma unroll
      for (int nj = 0; nj < 4; ++nj)
        Tr[(wave * 16 + lg * 4 + r) * 65 + nj * 16 + lm] = (unsigned int)lv[r][nj];
    __syncthreads();
#pragma unroll
    for (int q = 0; q < 2; ++q) {
      int f = tid + (q << 8);
      int d = f >> 3;
      int seg = (f & 7) << 3;
      unsigned int o[4];
#pragma unroll
      for (int k = 0; k < 4; ++k)
        o[k] = Tr[(seg + 2 * k) * 65 + d] | (Tr[(seg + 2 * k + 1) * 65 + d] << 16);
      *(uint4*)&Vtl[d * 8192 + rowBase + seg] = make_uint4(o[0], o[1], o[2], o[3]);
    }
  }
}

// ---------------------------------------------------------------------------
// MFMA attention core — EXACT R1 champion (47.7 us attn, 147.1 total).
// Grid = 1024: b(2) x sT(32) x slice(16). Block = 4 waves x 16 s-rows.
// Per chunk (8 chunks of 32 m): stage Kh/Kl/Vh/Vl (32x72) + Vth/Vtl (64x40),
// barrier, per-mj {QK/QV MFMAs, elementwise, W write to per-wave LDS},
// PV MFMAs (same-wave LDS), barrier. LDS = 33280 B -> 4 blocks/CU.
// Lessons pinned: slices=16 only (R2: 32 explodes atomic RMW 10x);
// no reg-prefetch (R3: neutral); K/V frags from LDS not global (R4: -60%);
// no LDS-trim/stride tricks (R5: regression).
// ---------------------------------------------------------------------------
__global__ void __attribute__((amdgpu_waves_per_eu(4)))
__launch_bounds__(256) attn_kernel(
    const float* __restrict__ Q0g, const unsigned short* __restrict__ Qh,
    const unsigned short* __restrict__ Ql,
    const float* __restrict__ K0g, const unsigned short* __restrict__ Khg,
    const unsigned short* __restrict__ Klg,
    const float* __restrict__ V0g, const unsigned short* __restrict__ Vhg,
    const unsigned short* __restrict__ Vlg,
    const unsigned short* __restrict__ Vthg, const unsigned short* __restrict__ Vtlg,
    float* __restrict__ Tacc, float* __restrict__ T0acc,
    float* __restrict__ Lacc, float* __restrict__ WCacc)
{
  // LDS layout (u16 units):
  //   Kh@0  Kl@2304  Vh@4608  Vl@6912   (each 32 rows x 72, 16B-aligned rows)
  //   Vth@9216  Vtl@11776               (each 64 rows x 40, 16B-aligned rows)
  //   W@14336 + wave*576                (per-wave 16 x 36, dedicated)
  __shared__ unsigned short LB[16640];   // 33280 B

  const int tid = threadIdx.x;
  const int wave = tid >> 6, lane = tid & 63;
  const int lm = lane & 15;
  const int lg = lane >> 4;
  const int bid = blockIdx.x;          // 1024 blocks
  const int slice = bid & 15;          // SL = 16
  const int t = bid >> 4;              // 0..63
  const int b = t >> 5;
  const int sT = t & 31;
  const int sBase = b * 2048 + sT * 64 + wave * 16;

  unsigned short* wbase = LB + 14336 + wave * 576;

  // loop-invariant Q fragments [kstep][hi/lo]
  short8 qf[2][2];
#pragma unroll
  for (int ks = 0; ks < 2; ++ks) {
    int idx = (sBase + lm) * 64 + ks * 32 + lg * 8;
    qf[ks][0] = *(const short8*)(Qh + idx);
    qf[ks][1] = *(const short8*)(Ql + idx);
  }
  float q0r[4];
#pragma unroll
  for (int r = 0; r < 4; ++r) q0r[r] = Q0g[sBase + lg * 4 + r];

  f32x4 accT[4];
  float Lp[4], WCp[4], T0p[4];
#pragma unroll
  for (int r = 0; r < 4; ++r) { Lp[r] = 0.f; WCp[r] = 0.f; T0p[r] = 0.f; }
#pragma unroll
  for (int dj = 0; dj < 4; ++dj) accT[dj] = f32x4{0.f, 0.f, 0.f, 0.f};

  const int mSliceBase = b * 4096 + slice * 256;   // 8 chunks of 32
  const int srow = tid >> 3;            // 0..31 (K/V tile row)
  const int sc8 = (tid & 7) << 3;       // 0,8,..,56
  const int drow = tid >> 2;            // 0..63 (Vt tile row = d)
  const int dseg = (tid & 3) << 3;      // 0,8,16,24

  for (int mc = 0; mc < 8; ++mc) {
    const int mCh = mSliceBase + (mc << 5);

    // ---- stage 6 tiles: one uint4 per thread per tile ----
    {
      int goff = (mCh + srow) * 64 + sc8;
      int loff = srow * 72 + sc8;
      *(uint4*)&LB[loff]         = *(const uint4*)&Khg[goff];
      *(uint4*)&LB[2304 + loff]  = *(const uint4*)&Klg[goff];
      *(uint4*)&LB[4608 + loff]  = *(const uint4*)&Vhg[goff];
      *(uint4*)&LB[6912 + loff]  = *(const uint4*)&Vlg[goff];
      int gofft = drow * 8192 + mCh + dseg;        // Vt global: [d][8192]
      int lofft = drow * 40 + dseg;
      *(uint4*)&LB[9216 + lofft]  = *(const uint4*)&Vthg[gofft];
      *(uint4*)&LB[11776 + lofft] = *(const uint4*)&Vtlg[gofft];
    }
    float k0r[2], v0r[2];
#pragma unroll
    for (int mj = 0; mj < 2; ++mj) {
      k0r[mj] = K0g[mCh + mj * 16 + lm];
      v0r[mj] = V0g[mCh + mj * 16 + lm];
    }
    __syncthreads();

    // ---- per m-block: sims/ipv MFMAs + elementwise + W write ----
#pragma unroll
    for (int mj = 0; mj < 2; ++mj) {
      f32x4 sims = f32x4{0.f, 0.f, 0.f, 0.f};
      f32x4 ipv  = f32x4{0.f, 0.f, 0.f, 0.f};
#pragma unroll
      for (int ks = 0; ks < 2; ++ks) {
        int off = (mj * 16 + lm) * 72 + ks * 32 + lg * 8;
        short8 kh = *(const short8*)&LB[off];
        short8 kl = *(const short8*)&LB[2304 + off];
        short8 vh = *(const short8*)&LB[4608 + off];
        short8 vl = *(const short8*)&LB[6912 + off];
        sims = __builtin_amdgcn_mfma_f32_16x16x32_bf16(qf[ks][0], kh, sims, 0, 0, 0);
        sims = __builtin_amdgcn_mfma_f32_16x16x32_bf16(qf[ks][0], kl, sims, 0, 0, 0);
        sims = __builtin_amdgcn_mfma_f32_16x16x32_bf16(qf[ks][1], kh, sims, 0, 0, 0);
        ipv  = __builtin_amdgcn_mfma_f32_16x16x32_bf16(qf[ks][0], vh, ipv, 0, 0, 0);
        ipv  = __builtin_amdgcn_mfma_f32_16x16x32_bf16(qf[ks][0], vl, ipv, 0, 0, 0);
        ipv  = __builtin_amdgcn_mfma_f32_16x16x32_bf16(qf[ks][1], vh, ipv, 0, 0, 0);
      }
      // w = e * acosh(-c) * rsq(c^2-1)
#pragma unroll
      for (int r = 0; r < 4; ++r) {
        float c  = ipv[r]  - q0r[r] * v0r[mj];
        float sm = sims[r] - q0r[r] * k0r[mj];
        float x = -c;
        float s2 = fmaxf(fmaf(x, x, -1.0f), EPSF);
        float rs = __builtin_amdgcn_rsqf(s2);
        float dist = __logf(fmaf(s2, rs, x));
        float e = __expf(fmaf(-BETA, sm, -SHIFT));
        float w = e * dist * rs;
        unsigned short wu = bf16_rne(w);
        float wb = bf16_tof(wu);
        Lp[r]  += e;
        WCp[r] += wb * c;
        T0p[r] += wb * v0r[mj];
        wbase[(lg * 4 + r) * 36 + mj * 16 + lm] = wu;
      }
    }

    // ---- Phase B: T[s][d] += W[s][m] * V[m][d]  (A=own-wave W, B=Vt) ----
    {
      short8 wa;
      {
        const unsigned short* p = wbase + lm * 36 + lg * 8;
        short4v a0 = *(const short4v*)p;
        short4v a1 = *(const short4v*)(p + 4);
        wa = __builtin_shufflevector(a0, a1, 0, 1, 2, 3, 4, 5, 6, 7);
      }
#pragma unroll
      for (int dj = 0; dj < 4; ++dj) {
        int off = (dj * 16 + lm) * 40 + lg * 8;
        short8 th = *(const short8*)&LB[9216 + off];
        short8 tl = *(const short8*)&LB[11776 + off];
        accT[dj] = __builtin_amdgcn_mfma_f32_16x16x32_bf16(wa, th, accT[dj], 0, 0, 0);
        accT[dj] = __builtin_amdgcn_mfma_f32_16x16x32_bf16(wa, tl, accT[dj], 0, 0, 0);
      }
    }
    __syncthreads();  // tiles consumed before next chunk's staging
  }

  // reduce row scalars across the 16 col-lanes
#pragma unroll
  for (int r = 0; r < 4; ++r)
#pragma unroll
    for (int off = 1; off < 16; off <<= 1) {
      Lp[r]  += __shfl_xor(Lp[r], off);
      WCp[r] += __shfl_xor(WCp[r], off);
      T0p[r] += __shfl_xor(T0p[r], off);
    }

  // atomic accumulation across slices (HW f32 atomics)
#pragma unroll
  for (int r = 0; r < 4; ++r) {
    int row = sBase + lg * 4 + r;
#pragma unroll
    for (int dj = 0; dj < 4; ++dj)
      unsafeAtomicAdd(&Tacc[row * 64 + dj * 16 + lm], accT[dj][r]);
    if (lm == 0) {
      unsafeAtomicAdd(&Lacc[row],  Lp[r]);
      unsafeAtomicAdd(&WCacc[row], WCp[r]);
      unsafeAtomicAdd(&T0acc[row], T0p[r]);
    }
  }
}

// ---------------------------------------------------------------------------
// Combine (r9-proven): one wave per (b,s) row. f32 fast math; f64 only for
// the <t,t> reduction feeding the tangency identity mk = <t,t> + wc^2.
// ---------------------------------------------------------------------------
__global__ __launch_bounds__(256) void combine_kernel(
    const float* __restrict__ Q0, const unsigned short* __restrict__ Qh,
    const unsigned short* __restrict__ Ql,
    const float* __restrict__ Tacc, const float* __restrict__ T0acc,
    const float* __restrict__ Lacc, const float* __restrict__ WCacc,
    float* __restrict__ out)
{
  int wid = (blockIdx.x << 2) + (threadIdx.x >> 6);
  int lane = threadIdx.x & 63;

  int qi = wid * 64 + lane;
  float Tsum = Tacc[qi];
  float T0 = T0acc[wid];
  float L  = Lacc[wid];
  float WC = WCacc[wid];

  float qd = bf16_tof(Qh[qi]) + bf16_tof(Ql[qi]);
  float q0 = Q0[wid];
  float invL = 1.0f / L;
  float td = Tsum * invL;
  float t0 = T0 * invL;
  float wc = WC * invL;

  double tt = (double)td * (double)td;
#pragma unroll
  for (int off = 1; off < 64; off <<= 1) tt += __shfl_xor(tt, off);
  tt -= (double)t0 * (double)t0;
  double mk = tt + (double)wc * (double)wc;

  float un = (float)sqrt(fmax(mk, 1e-12));
  float eu = __expf(un);
  float ru = 1.0f / eu;
  float ch = 0.5f * (eu + ru);
  float shu = 0.5f * (eu - ru) / un;

  float tmd = td + wc * qd;
  float tm0 = t0 + wc * q0;
  float zd = ch * qd + shu * tmd;
  float z0 = ch * q0 + shu * tm0;

  float p2 = zd * zd;
#pragma unroll
  for (int off = 1; off < 64; off <<= 1) p2 += __shfl_xor(p2, off);
  float yn = fmaxf(sqrtf(p2), EPSF);
  float zc = fmaxf(z0, 1.0f + EPSF);
  float dl = __logf(zc + sqrtf(fmaxf(zc * zc - 1.0f, 0.f)));
  out[qi] = dl * zd / yn;
}

// ---------------------------------------------------------------------------
extern "C" void kernel_launch(void* const* d_in, const int* in_sizes, int n_in,
                              void* d_out, int out_size, void* d_ws, size_t ws_size,
                              hipStream_t stream)
{
  const float* queries = (const float*)d_in[0];
  const float* keys    = (const float*)d_in[1];
  const float* values  = (const float*)d_in[2];
  const float* Wq      = (const float*)d_in[3];
  const float* bq      = (const float*)d_in[4];
  const float* Wk      = (const float*)d_in[5];
  const float* bk      = (const float*)d_in[6];
  const float* Wv      = (const float*)d_in[7];
  const float* bv      = (const float*)d_in[8];
  float* out = (float*)d_out;
  float* ws  = (float*)d_ws;

  float* Q0 = ws;                                   // 4096
  float* K0 = ws + 4096;                            // 8192
  float* V0 = ws + 12288;                           // 8192
  unsigned short* Qh  = (unsigned short*)(ws + 20480);
  unsigned short* Ql  = (unsigned short*)(ws + 151552);
  unsigned short* Kh  = (unsigned short*)(ws + 282624);
  unsigned short* Kl  = (unsigned short*)(ws + 544768);
  unsigned short* Vh  = (unsigned short*)(ws + 806912);
  unsigned short* Vl  = (unsigned short*)(ws + 1069056);
  unsigned short* Vth = (unsigned short*)(ws + 1331200);  // [64][8192]
  unsigned short* Vtl = (unsigned short*)(ws + 1593344);
  float* Tacc  = ws + 1855488;                      // 4096*64 = 262144
  float* T0acc = ws + 2117632;                      // 4096
  float* Lacc  = ws + 2121728;                      // 4096
  float* WCacc = ws + 2125824;                      // 4096

  proj_kernel<<<320, 256, 0, stream>>>(queries, keys, values, Wq, bq, Wk, bk,
                                       Wv, bv, Q0, K0, V0, Qh, Ql, Kh, Kl,
                                       Vh, Vl, Vth, Vtl, Tacc);
  attn_kernel<<<1024, 256, 0, stream>>>(
      Q0, Qh, Ql, K0, Kh, Kl, V0, Vh, Vl, Vth, Vtl,
      Tacc, T0acc, Lacc, WCacc);
  combine_kernel<<<1024, 256, 0, stream>>>(
      Q0, Qh, Ql, Tacc, T0acc, Lacc, WCacc, out);
}

// Round 7
// 135.195 us; speedup vs baseline: 1.2909x; 1.0699x over previous
//
#include <hip/hip_runtime.h>
#include <math.h>

#define BETA  0.125f    // 1/sqrt(64)
#define SHIFT 30.0f     // fixed softmax shift; logits bounded in [0.125, 68.5]
#define EPSF  1e-7f

typedef __attribute__((ext_vector_type(8))) short short8;
typedef __attribute__((ext_vector_type(4))) short short4v;
typedef __attribute__((ext_vector_type(4))) float f32x4;

__device__ __forceinline__ unsigned short bf16_rne(float x) {
  unsigned int u = __float_as_uint(x);
  return (unsigned short)((u + 0x7fffu + ((u >> 16) & 1u)) >> 16);
}
__device__ __forceinline__ float bf16_tof(unsigned short h) {
  return __uint_as_float(((unsigned int)h) << 16);
}
__device__ __forceinline__ void split2(float x, unsigned short& h, unsigned short& l) {
  unsigned int u = __float_as_uint(x);
  unsigned int hr = (u + 0x7fffu + ((u >> 16) & 1u)) & 0xffff0000u;  // RNE hi
  h = (unsigned short)(hr >> 16);
  l = bf16_rne(x - __uint_as_float(hr));
}
// split a float4 into hi/lo bf16 and store 8B to each LDS tile
__device__ __forceinline__ void store4(unsigned short* ph, unsigned short* pl, float4 v) {
  unsigned short h0, h1, h2, h3, l0, l1, l2, l3;
  split2(v.x, h0, l0); split2(v.y, h1, l1);
  split2(v.z, h2, l2); split2(v.w, h3, l3);
  *(uint2*)ph = make_uint2((unsigned)h0 | ((unsigned)h1 << 16),
                           (unsigned)h2 | ((unsigned)h3 << 16));
  *(uint2*)pl = make_uint2((unsigned)l0 | ((unsigned)l1 << 16),
                           (unsigned)l2 | ((unsigned)l3 << 16));
}

#define ZERO_F4 68608   // (262144 + 12288) floats / 4: Tacc + scalar accums

// ---------------------------------------------------------------------------
// MFMA projection v2 — coalesced LDS staging (fixes R6's exposed-latency
// gathers: MfmaUtil was 1.3%, every A/B fragment a 16-row global gather).
// Per kc (4 rounds of 64 cols): stage X-slice + W-slice with coalesced
// float4 loads, split to hi/lo bf16 ONCE, store as [64][72]-u16 LDS tiles
// (stride 72: rows 16B-aligned, 2-way bank aliasing = free). MFMA B/A frags
// then read from LDS (b128). V's stage-2 GEMM (K=64): Vk-split + Wv staged
// into the SAME overlaid LDS region; Tr transpose overlays it too.
// Numerics identical to R6 (same split + MFMA sequence) -> absmax unchanged.
// Blocks 0..127: V (2 GEMMs, scheduled first); 128..255: K; 256..319: Q.
// Also zeroes the attention accumulator region.
// ---------------------------------------------------------------------------
__global__ __launch_bounds__(256) void proj_kernel(
    const float* __restrict__ Xq, const float* __restrict__ Xk,
    const float* __restrict__ Xv,
    const float* __restrict__ Wq, const float* __restrict__ bq,
    const float* __restrict__ Wk, const float* __restrict__ bk,
    const float* __restrict__ Wv, const float* __restrict__ bv,
    float* __restrict__ Q0, float* __restrict__ K0, float* __restrict__ V0,
    unsigned short* __restrict__ Qh, unsigned short* __restrict__ Ql,
    unsigned short* __restrict__ Kh, unsigned short* __restrict__ Kl,
    unsigned short* __restrict__ Vh, unsigned short* __restrict__ Vl,
    unsigned short* __restrict__ Vth, unsigned short* __restrict__ Vtl,
    float* __restrict__ zeroRegion)
{
  // One overlaid region, 18432 u16 = 36,864 B. Phases (barrier-separated):
  //  GEMM1 per kc:  Xh@0  Xl@4608  Wh@9216  Wl@13824   (each [64][72])
  //  stage2 (V):    VkH@0 VkL@4608 WvH@9216 WvL@13824
  //  transpose (V): Tr = (unsigned int*)LB, [64][65]
  __shared__ unsigned short LB[18432];

  const int bid = blockIdx.x;
  const int tid = threadIdx.x;

  {
    int idx = bid * 256 + tid;
    if (idx < ZERO_F4)
      *(float4*)&zeroRegion[idx * 4] = make_float4(0.f, 0.f, 0.f, 0.f);
  }

  const float *X, *W, *bias;
  float* y0;
  unsigned short *yh, *yl;
  bool dbl;
  int rowBase;
  if (bid < 128)      { X = Xv; W = Wk; bias = bk; y0 = V0; yh = Vh; yl = Vl; rowBase = bid << 6;         dbl = true;  }
  else if (bid < 256) { X = Xk; W = Wk; bias = bk; y0 = K0; yh = Kh; yl = Kl; rowBase = (bid - 128) << 6; dbl = false; }
  else                { X = Xq; W = Wq; bias = bq; y0 = Q0; yh = Qh; yl = Ql; rowBase = (bid - 256) << 6; dbl = false; }

  const int wave = tid >> 6, lane = tid & 63;
  const int lm = lane & 15;
  const int lg = lane >> 4;
  const int rowB = rowBase + (wave << 4);   // this wave's 16 output rows

  f32x4 acc[4];
#pragma unroll
  for (int nj = 0; nj < 4; ++nj) {
    float b = bias[nj * 16 + lm];
    acc[nj] = f32x4{b, b, b, b};
  }

  // ---- stage-1 GEMM: acc[nj] = X . W^T + bias (K=256, 4 kc rounds) ----
  for (int kc = 0; kc < 4; ++kc) {
#pragma unroll
    for (int q = 0; q < 4; ++q) {
      int f = tid + (q << 8);
      int r = f >> 4, g = f & 15;           // row 0..63, col-group 0..15
      float4 xv = *(const float4*)&X[(rowBase + r) * 256 + (kc << 6) + (g << 2)];
      float4 wv = *(const float4*)&W[r * 256 + (kc << 6) + (g << 2)];
      int o = r * 72 + (g << 2);
      store4(&LB[o],         &LB[4608 + o],  xv);
      store4(&LB[9216 + o],  &LB[13824 + o], wv);
    }
    __syncthreads();
    short8 Ah2[2], Al2[2];
#pragma unroll
    for (int ks = 0; ks < 2; ++ks) {
      int ao = (wave * 16 + lm) * 72 + ks * 32 + lg * 8;
      Ah2[ks] = *(const short8*)&LB[ao];
      Al2[ks] = *(const short8*)&LB[4608 + ao];
    }
#pragma unroll
    for (int nj = 0; nj < 4; ++nj) {
#pragma unroll
      for (int ks = 0; ks < 2; ++ks) {
        int bo = (nj * 16 + lm) * 72 + ks * 32 + lg * 8;
        short8 Bh = *(const short8*)&LB[9216 + bo];
        short8 Bl = *(const short8*)&LB[13824 + bo];
        acc[nj] = __builtin_amdgcn_mfma_f32_16x16x32_bf16(Ah2[ks], Bh, acc[nj], 0, 0, 0);
        acc[nj] = __builtin_amdgcn_mfma_f32_16x16x32_bf16(Ah2[ks], Bl, acc[nj], 0, 0, 0);
        acc[nj] = __builtin_amdgcn_mfma_f32_16x16x32_bf16(Al2[ks], Bh, acc[nj], 0, 0, 0);
      }
    }
    __syncthreads();   // tiles consumed before next kc's staging
  }

  // ---- stage-2 for V: Ve = Vk . Wv^T + bv (K=64), LDS-staged ----
  if (dbl) {
    // write Vk (split) into VkH/VkL; stage Wv coalesced into WvH/WvL
#pragma unroll
    for (int nj = 0; nj < 4; ++nj)
#pragma unroll
      for (int r = 0; r < 4; ++r) {
        unsigned short h, l;
        split2(acc[nj][r], h, l);
        int ro = (wave * 16 + lg * 4 + r) * 72 + nj * 16 + lm;
        LB[ro] = h;
        LB[4608 + ro] = l;
      }
#pragma unroll
    for (int q = 0; q < 4; ++q) {
      int f = tid + (q << 8);
      int r = f >> 4, g = f & 15;
      float4 wv = *(const float4*)&Wv[r * 64 + (g << 2)];
      int o = r * 72 + (g << 2);
      store4(&LB[9216 + o], &LB[13824 + o], wv);
    }
    __syncthreads();
    short8 A2h[2], A2l[2];
#pragma unroll
    for (int ks = 0; ks < 2; ++ks) {
      int ao = (wave * 16 + lm) * 72 + ks * 32 + lg * 8;
      A2h[ks] = *(const short8*)&LB[ao];
      A2l[ks] = *(const short8*)&LB[4608 + ao];
    }
#pragma unroll
    for (int nj = 0; nj < 4; ++nj) {
      float b = bv[nj * 16 + lm];
      acc[nj] = f32x4{b, b, b, b};
    }
#pragma unroll
    for (int nj = 0; nj < 4; ++nj) {
#pragma unroll
      for (int ks = 0; ks < 2; ++ks) {
        int bo = (nj * 16 + lm) * 72 + ks * 32 + lg * 8;
        short8 Bh = *(const short8*)&LB[9216 + bo];
        short8 Bl = *(const short8*)&LB[13824 + bo];
        acc[nj] = __builtin_amdgcn_mfma_f32_16x16x32_bf16(A2h[ks], Bh, acc[nj], 0, 0, 0);
        acc[nj] = __builtin_amdgcn_mfma_f32_16x16x32_bf16(A2h[ks], Bl, acc[nj], 0, 0, 0);
        acc[nj] = __builtin_amdgcn_mfma_f32_16x16x32_bf16(A2l[ks], Bh, acc[nj], 0, 0, 0);
      }
    }
  }

  // ---- expmap0 epilogue: row = rowB + lg*4 + r, cols nj*16 + lm ----
  float n2p[4];
#pragma unroll
  for (int r = 0; r < 4; ++r)
    n2p[r] = acc[0][r] * acc[0][r] + acc[1][r] * acc[1][r] +
             acc[2][r] * acc[2][r] + acc[3][r] * acc[3][r];
#pragma unroll
  for (int r = 0; r < 4; ++r) {
    n2p[r] += __shfl_xor(n2p[r], 1);
    n2p[r] += __shfl_xor(n2p[r], 2);
    n2p[r] += __shfl_xor(n2p[r], 4);
    n2p[r] += __shfl_xor(n2p[r], 8);
  }
  unsigned short hv[4][4], lv[4][4];   // [r][nj]
#pragma unroll
  for (int r = 0; r < 4; ++r) {
    float n = sqrtf(n2p[r]);
    float factor = fminf(3.5f / (n + EPSF), 1.0f);
    float xn = fmaxf(n * factor, EPSF);
    float et = __expf(xn);
    float rt = __builtin_amdgcn_rcpf(et);
    float ch = 0.5f * (et + rt);
    float sh = 0.5f * (et - rt);
    float scale = sh * factor * __builtin_amdgcn_rcpf(xn);
    int row = rowB + lg * 4 + r;
    if (lm == 0) y0[row] = ch;
#pragma unroll
    for (int nj = 0; nj < 4; ++nj) {
      split2(acc[nj][r] * scale, hv[r][nj], lv[r][nj]);
      yh[row * 64 + nj * 16 + lm] = hv[r][nj];
      yl[row * 64 + nj * 16 + lm] = lv[r][nj];
    }
  }

  // ---- V transposed copies via Tr overlay (two passes: hi, lo) ----
  if (dbl) {
    __syncthreads();   // all waves done reading VkL/Wv before Tr overlay
    unsigned int* Tr = (unsigned int*)LB;   // [64][65]
#pragma unroll
    for (int r = 0; r < 4; ++r)
#pragma unroll
      for (int nj = 0; nj < 4; ++nj)
        Tr[(wave * 16 + lg * 4 + r) * 65 + nj * 16 + lm] = (unsigned int)hv[r][nj];
    __syncthreads();
#pragma unroll
    for (int q = 0; q < 2; ++q) {
      int f = tid + (q << 8);
      int d = f >> 3;
      int seg = (f & 7) << 3;
      unsigned int o[4];
#pragma unroll
      for (int k = 0; k < 4; ++k)
        o[k] = Tr[(seg + 2 * k) * 65 + d] | (Tr[(seg + 2 * k + 1) * 65 + d] << 16);
      *(uint4*)&Vth[d * 8192 + rowBase + seg] = make_uint4(o[0], o[1], o[2], o[3]);
    }
    __syncthreads();
#pragma unroll
    for (int r = 0; r < 4; ++r)
#pragma unroll
      for (int nj = 0; nj < 4; ++nj)
        Tr[(wave * 16 + lg * 4 + r) * 65 + nj * 16 + lm] = (unsigned int)lv[r][nj];
    __syncthreads();
#pragma unroll
    for (int q = 0; q < 2; ++q) {
      int f = tid + (q << 8);
      int d = f >> 3;
      int seg = (f & 7) << 3;
      unsigned int o[4];
#pragma unroll
      for (int k = 0; k < 4; ++k)
        o[k] = Tr[(seg + 2 * k) * 65 + d] | (Tr[(seg + 2 * k + 1) * 65 + d] << 16);
      *(uint4*)&Vtl[d * 8192 + rowBase + seg] = make_uint4(o[0], o[1], o[2], o[3]);
    }
  }
}

// ---------------------------------------------------------------------------
// MFMA attention core — EXACT R1 champion structure (best measured attn).
// Grid = 1024: b(2) x sT(32) x slice(16). Block = 4 waves x 16 s-rows.
// Per chunk (8 chunks of 32 m): stage Kh/Kl/Vh/Vl (32x72) + Vth/Vtl (64x40),
// barrier, per-mj {QK/QV MFMAs, elementwise, W write to per-wave LDS},
// PV MFMAs (same-wave LDS), barrier. LDS = 33280 B -> 4 blocks/CU.
// Lessons pinned: slices=16 only (R2: 32 explodes atomic RMW 10x);
// no reg-prefetch (R3: neutral); K/V frags from LDS not global (R4: -60%);
// no LDS-trim/stride tricks (R5: regression).
// ---------------------------------------------------------------------------
__global__ void __attribute__((amdgpu_waves_per_eu(4)))
__launch_bounds__(256) attn_kernel(
    const float* __restrict__ Q0g, const unsigned short* __restrict__ Qh,
    const unsigned short* __restrict__ Ql,
    const float* __restrict__ K0g, const unsigned short* __restrict__ Khg,
    const unsigned short* __restrict__ Klg,
    const float* __restrict__ V0g, const unsigned short* __restrict__ Vhg,
    const unsigned short* __restrict__ Vlg,
    const unsigned short* __restrict__ Vthg, const unsigned short* __restrict__ Vtlg,
    float* __restrict__ Tacc, float* __restrict__ T0acc,
    float* __restrict__ Lacc, float* __restrict__ WCacc)
{
  // LDS layout (u16 units):
  //   Kh@0  Kl@2304  Vh@4608  Vl@6912   (each 32 rows x 72, 16B-aligned rows)
  //   Vth@9216  Vtl@11776               (each 64 rows x 40, 16B-aligned rows)
  //   W@14336 + wave*576                (per-wave 16 x 36, dedicated)
  __shared__ unsigned short LB[16640];   // 33280 B

  const int tid = threadIdx.x;
  const int wave = tid >> 6, lane = tid & 63;
  const int lm = lane & 15;
  const int lg = lane >> 4;
  const int bid = blockIdx.x;          // 1024 blocks
  const int slice = bid & 15;          // SL = 16
  const int t = bid >> 4;              // 0..63
  const int b = t >> 5;
  const int sT = t & 31;
  const int sBase = b * 2048 + sT * 64 + wave * 16;

  unsigned short* wbase = LB + 14336 + wave * 576;

  // loop-invariant Q fragments [kstep][hi/lo]
  short8 qf[2][2];
#pragma unroll
  for (int ks = 0; ks < 2; ++ks) {
    int idx = (sBase + lm) * 64 + ks * 32 + lg * 8;
    qf[ks][0] = *(const short8*)(Qh + idx);
    qf[ks][1] = *(const short8*)(Ql + idx);
  }
  float q0r[4];
#pragma unroll
  for (int r = 0; r < 4; ++r) q0r[r] = Q0g[sBase + lg * 4 + r];

  f32x4 accT[4];
  float Lp[4], WCp[4], T0p[4];
#pragma unroll
  for (int r = 0; r < 4; ++r) { Lp[r] = 0.f; WCp[r] = 0.f; T0p[r] = 0.f; }
#pragma unroll
  for (int dj = 0; dj < 4; ++dj) accT[dj] = f32x4{0.f, 0.f, 0.f, 0.f};

  const int mSliceBase = b * 4096 + slice * 256;   // 8 chunks of 32
  const int srow = tid >> 3;            // 0..31 (K/V tile row)
  const int sc8 = (tid & 7) << 3;       // 0,8,..,56
  const int drow = tid >> 2;            // 0..63 (Vt tile row = d)
  const int dseg = (tid & 3) << 3;      // 0,8,16,24

  for (int mc = 0; mc < 8; ++mc) {
    const int mCh = mSliceBase + (mc << 5);

    // ---- stage 6 tiles: one uint4 per thread per tile ----
    {
      int goff = (mCh + srow) * 64 + sc8;
      int loff = srow * 72 + sc8;
      *(uint4*)&LB[loff]         = *(const uint4*)&Khg[goff];
      *(uint4*)&LB[2304 + loff]  = *(const uint4*)&Klg[goff];
      *(uint4*)&LB[4608 + loff]  = *(const uint4*)&Vhg[goff];
      *(uint4*)&LB[6912 + loff]  = *(const uint4*)&Vlg[goff];
      int gofft = drow * 8192 + mCh + dseg;        // Vt global: [d][8192]
      int lofft = drow * 40 + dseg;
      *(uint4*)&LB[9216 + lofft]  = *(const uint4*)&Vthg[gofft];
      *(uint4*)&LB[11776 + lofft] = *(const uint4*)&Vtlg[gofft];
    }
    float k0r[2], v0r[2];
#pragma unroll
    for (int mj = 0; mj < 2; ++mj) {
      k0r[mj] = K0g[mCh + mj * 16 + lm];
      v0r[mj] = V0g[mCh + mj * 16 + lm];
    }
    __syncthreads();

    // ---- per m-block: sims/ipv MFMAs + elementwise + W write ----
#pragma unroll
    for (int mj = 0; mj < 2; ++mj) {
      f32x4 sims = f32x4{0.f, 0.f, 0.f, 0.f};
      f32x4 ipv  = f32x4{0.f, 0.f, 0.f, 0.f};
#pragma unroll
      for (int ks = 0; ks < 2; ++ks) {
        int off = (mj * 16 + lm) * 72 + ks * 32 + lg * 8;
        short8 kh = *(const short8*)&LB[off];
        short8 kl = *(const short8*)&LB[2304 + off];
        short8 vh = *(const short8*)&LB[4608 + off];
        short8 vl = *(const short8*)&LB[6912 + off];
        sims = __builtin_amdgcn_mfma_f32_16x16x32_bf16(qf[ks][0], kh, sims, 0, 0, 0);
        sims = __builtin_amdgcn_mfma_f32_16x16x32_bf16(qf[ks][0], kl, sims, 0, 0, 0);
        sims = __builtin_amdgcn_mfma_f32_16x16x32_bf16(qf[ks][1], kh, sims, 0, 0, 0);
        ipv  = __builtin_amdgcn_mfma_f32_16x16x32_bf16(qf[ks][0], vh, ipv, 0, 0, 0);
        ipv  = __builtin_amdgcn_mfma_f32_16x16x32_bf16(qf[ks][0], vl, ipv, 0, 0, 0);
        ipv  = __builtin_amdgcn_mfma_f32_16x16x32_bf16(qf[ks][1], vh, ipv, 0, 0, 0);
      }
      // w = e * acosh(-c) * rsq(c^2-1)
#pragma unroll
      for (int r = 0; r < 4; ++r) {
        float c  = ipv[r]  - q0r[r] * v0r[mj];
        float sm = sims[r] - q0r[r] * k0r[mj];
        float x = -c;
        float s2 = fmaxf(fmaf(x, x, -1.0f), EPSF);
        float rs = __builtin_amdgcn_rsqf(s2);
        float dist = __logf(fmaf(s2, rs, x));
        float e = __expf(fmaf(-BETA, sm, -SHIFT));
        float w = e * dist * rs;
        unsigned short wu = bf16_rne(w);
        float wb = bf16_tof(wu);
        Lp[r]  += e;
        WCp[r] += wb * c;
        T0p[r] += wb * v0r[mj];
        wbase[(lg * 4 + r) * 36 + mj * 16 + lm] = wu;
      }
    }

    // ---- Phase B: T[s][d] += W[s][m] * V[m][d]  (A=own-wave W, B=Vt) ----
    {
      short8 wa;
      {
        const unsigned short* p = wbase + lm * 36 + lg * 8;
        short4v a0 = *(const short4v*)p;
        short4v a1 = *(const short4v*)(p + 4);
        wa = __builtin_shufflevector(a0, a1, 0, 1, 2, 3, 4, 5, 6, 7);
      }
#pragma unroll
      for (int dj = 0; dj < 4; ++dj) {
        int off = (dj * 16 + lm) * 40 + lg * 8;
        short8 th = *(const short8*)&LB[9216 + off];
        short8 tl = *(const short8*)&LB[11776 + off];
        accT[dj] = __builtin_amdgcn_mfma_f32_16x16x32_bf16(wa, th, accT[dj], 0, 0, 0);
        accT[dj] = __builtin_amdgcn_mfma_f32_16x16x32_bf16(wa, tl, accT[dj], 0, 0, 0);
      }
    }
    __syncthreads();  // tiles consumed before next chunk's staging
  }

  // reduce row scalars across the 16 col-lanes
#pragma unroll
  for (int r = 0; r < 4; ++r)
#pragma unroll
    for (int off = 1; off < 16; off <<= 1) {
      Lp[r]  += __shfl_xor(Lp[r], off);
      WCp[r] += __shfl_xor(WCp[r], off);
      T0p[r] += __shfl_xor(T0p[r], off);
    }

  // atomic accumulation across slices (HW f32 atomics)
#pragma unroll
  for (int r = 0; r < 4; ++r) {
    int row = sBase + lg * 4 + r;
#pragma unroll
    for (int dj = 0; dj < 4; ++dj)
      unsafeAtomicAdd(&Tacc[row * 64 + dj * 16 + lm], accT[dj][r]);
    if (lm == 0) {
      unsafeAtomicAdd(&Lacc[row],  Lp[r]);
      unsafeAtomicAdd(&WCacc[row], WCp[r]);
      unsafeAtomicAdd(&T0acc[row], T0p[r]);
    }
  }
}

// ---------------------------------------------------------------------------
// Combine (r9-proven): one wave per (b,s) row. f32 fast math; f64 only for
// the <t,t> reduction feeding the tangency identity mk = <t,t> + wc^2.
// ---------------------------------------------------------------------------
__global__ __launch_bounds__(256) void combine_kernel(
    const float* __restrict__ Q0, const unsigned short* __restrict__ Qh,
    const unsigned short* __restrict__ Ql,
    const float* __restrict__ Tacc, const float* __restrict__ T0acc,
    const float* __restrict__ Lacc, const float* __restrict__ WCacc,
    float* __restrict__ out)
{
  int wid = (blockIdx.x << 2) + (threadIdx.x >> 6);
  int lane = threadIdx.x & 63;

  int qi = wid * 64 + lane;
  float Tsum = Tacc[qi];
  float T0 = T0acc[wid];
  float L  = Lacc[wid];
  float WC = WCacc[wid];

  float qd = bf16_tof(Qh[qi]) + bf16_tof(Ql[qi]);
  float q0 = Q0[wid];
  float invL = 1.0f / L;
  float td = Tsum * invL;
  float t0 = T0 * invL;
  float wc = WC * invL;

  double tt = (double)td * (double)td;
#pragma unroll
  for (int off = 1; off < 64; off <<= 1) tt += __shfl_xor(tt, off);
  tt -= (double)t0 * (double)t0;
  double mk = tt + (double)wc * (double)wc;

  float un = (float)sqrt(fmax(mk, 1e-12));
  float eu = __expf(un);
  float ru = 1.0f / eu;
  float ch = 0.5f * (eu + ru);
  float shu = 0.5f * (eu - ru) / un;

  float tmd = td + wc * qd;
  float tm0 = t0 + wc * q0;
  float zd = ch * qd + shu * tmd;
  float z0 = ch * q0 + shu * tm0;

  float p2 = zd * zd;
#pragma unroll
  for (int off = 1; off < 64; off <<= 1) p2 += __shfl_xor(p2, off);
  float yn = fmaxf(sqrtf(p2), EPSF);
  float zc = fmaxf(z0, 1.0f + EPSF);
  float dl = __logf(zc + sqrtf(fmaxf(zc * zc - 1.0f, 0.f)));
  out[qi] = dl * zd / yn;
}

// ---------------------------------------------------------------------------
extern "C" void kernel_launch(void* const* d_in, const int* in_sizes, int n_in,
                              void* d_out, int out_size, void* d_ws, size_t ws_size,
                              hipStream_t stream)
{
  const float* queries = (const float*)d_in[0];
  const float* keys    = (const float*)d_in[1];
  const float* values  = (const float*)d_in[2];
  const float* Wq      = (const float*)d_in[3];
  const float* bq      = (const float*)d_in[4];
  const float* Wk      = (const float*)d_in[5];
  const float* bk      = (const float*)d_in[6];
  const float* Wv      = (const float*)d_in[7];
  const float* bv      = (const float*)d_in[8];
  float* out = (float*)d_out;
  float* ws  = (float*)d_ws;

  float* Q0 = ws;                                   // 4096
  float* K0 = ws + 4096;                            // 8192
  float* V0 = ws + 12288;                           // 8192
  unsigned short* Qh  = (unsigned short*)(ws + 20480);
  unsigned short* Ql  = (unsigned short*)(ws + 151552);
  unsigned short* Kh  = (unsigned short*)(ws + 282624);
  unsigned short* Kl  = (unsigned short*)(ws + 544768);
  unsigned short* Vh  = (unsigned short*)(ws + 806912);
  unsigned short* Vl  = (unsigned short*)(ws + 1069056);
  unsigned short* Vth = (unsigned short*)(ws + 1331200);  // [64][8192]
  unsigned short* Vtl = (unsigned short*)(ws + 1593344);
  float* Tacc  = ws + 1855488;                      // 4096*64 = 262144
  float* T0acc = ws + 2117632;                      // 4096
  float* Lacc  = ws + 2121728;                      // 4096
  float* WCacc = ws + 2125824;                      // 4096

  proj_kernel<<<320, 256, 0, stream>>>(queries, keys, values, Wq, bq, Wk, bk,
                                       Wv, bv, Q0, K0, V0, Qh, Ql, Kh, Kl,
                                       Vh, Vl, Vth, Vtl, Tacc);
  attn_kernel<<<1024, 256, 0, stream>>>(
      Q0, Qh, Ql, K0, Kh, Kl, V0, Vh, Vl, Vth, Vtl,
      Tacc, T0acc, Lacc, WCacc);
  combine_kernel<<<1024, 256, 0, stream>>>(
      Q0, Qh, Ql, Tacc, T0acc, Lacc, WCacc, out);
}